// Round 12
// baseline (832.570 us; speedup 1.0000x reference)
//
#include <hip/hip_runtime.h>
#include <hip/hip_bf16.h>
#include <stdint.h>

typedef __bf16 bf16;
typedef __bf16 bf16x8 __attribute__((ext_vector_type(8)));
typedef float  f32x4v __attribute__((ext_vector_type(4)));

__device__ __forceinline__ void cvt8(const float* v, bf16x8& hh, bf16x8& ll) {
    #pragma unroll
    for (int j = 0; j < 8; j++) {
        bf16 b = (bf16)v[j]; hh[j] = b; ll[j] = (bf16)(v[j] - (float)b);
    }
}

// ---------------------------------------------------------------- reductions
__device__ __forceinline__ float block_reduce_sum256(float v) {
    __shared__ float red[256];
    int tid = threadIdx.x;
    red[tid] = v; __syncthreads();
    #pragma unroll
    for (int s = 128; s > 0; s >>= 1) {
        if (tid < s) red[tid] += red[tid + s];
        __syncthreads();
    }
    float r = red[0]; __syncthreads();
    return r;
}

// ---------------------------------------------------------------- bf16x3 split-MFMA GEMM (legacy: f32 A+B, in-kernel convert)
template<int BMT, bool RELU, bool TRANS, bool BNAT, bool HILO>
__global__ __launch_bounds__(256, 2)
void gemm3(const float* __restrict__ A, const float* __restrict__ B,
           const float* __restrict__ bias, float* __restrict__ C,
           bf16* __restrict__ Chi, bf16* __restrict__ Clo,
           int K, int lda, int ldb, int ldc, float alpha)
{
    constexpr int BN = 128, TK = 32;
    constexpr int RM = BMT / 32;
    __shared__ __align__(16) bf16 Ah[BMT * TK];
    __shared__ __align__(16) bf16 Al[BMT * TK];
    __shared__ __align__(16) bf16 Bh[BN * TK];
    __shared__ __align__(16) bf16 Bl[BN * TK];

    const int tid  = threadIdx.x;
    const int wave = tid >> 6, lane = tid & 63;
    const int wr = wave >> 1, wc = wave & 1;
    const long bm = (long)blockIdx.y * BMT;
    const long bn = (long)blockIdx.x * BN;
    const int fr = lane & 15, fq = lane >> 4;

    f32x4v acc[RM][4] = {};

    for (int k0 = 0; k0 < K; k0 += TK) {
        #pragma unroll
        for (int it = 0; it < BMT / 64; it++) {
            const int c = it * 256 + tid;
            const int r = c >> 2, k8 = c & 3;
            const float* src = A + (bm + r) * (long)lda + k0 + k8 * 8;
            float4 f0 = ((const float4*)src)[0], f1 = ((const float4*)src)[1];
            float v[8] = {f0.x, f0.y, f0.z, f0.w, f1.x, f1.y, f1.z, f1.w};
            bf16x8 hh, ll; cvt8(v, hh, ll);
            *(bf16x8*)&Ah[r * TK + k8 * 8] = hh;
            *(bf16x8*)&Al[r * TK + k8 * 8] = ll;
        }
        if (BNAT) {
            const int col = tid & 127, bkh = (tid >> 7) * 16;
            const float* src = B + (long)(k0 + bkh) * ldb + bn + col;
            float v[16];
            #pragma unroll
            for (int kk = 0; kk < 16; kk++) v[kk] = src[(long)kk * ldb];
            bf16x8 h0, l0, h1, l1; cvt8(v, h0, l0); cvt8(v + 8, h1, l1);
            bf16* hd = &Bh[col * TK + bkh];
            bf16* ld_ = &Bl[col * TK + bkh];
            ((bf16x8*)hd)[0] = h0; ((bf16x8*)hd)[1] = h1;
            ((bf16x8*)ld_)[0] = l0; ((bf16x8*)ld_)[1] = l1;
        } else {
            #pragma unroll
            for (int it = 0; it < 2; it++) {
                const int c = it * 256 + tid;
                const int r = c >> 2, k8 = c & 3;
                const float* src = B + (bn + r) * (long)ldb + k0 + k8 * 8;
                float4 f0 = ((const float4*)src)[0], f1 = ((const float4*)src)[1];
                float v[8] = {f0.x, f0.y, f0.z, f0.w, f1.x, f1.y, f1.z, f1.w};
                bf16x8 hh, ll; cvt8(v, hh, ll);
                *(bf16x8*)&Bh[r * TK + k8 * 8] = hh;
                *(bf16x8*)&Bl[r * TK + k8 * 8] = ll;
            }
        }
        __syncthreads();

        bf16x8 ah[RM], am[RM], bh[4], bm_[4];
        #pragma unroll
        for (int i = 0; i < RM; i++) {
            const int r = (wr * (BMT / 2) + i * 16 + fr) * TK + fq * 8;
            ah[i] = *(const bf16x8*)&Ah[r];
            am[i] = *(const bf16x8*)&Al[r];
        }
        #pragma unroll
        for (int j = 0; j < 4; j++) {
            const int r = (wc * 64 + j * 16 + fr) * TK + fq * 8;
            bh[j] = *(const bf16x8*)&Bh[r];
            bm_[j] = *(const bf16x8*)&Bl[r];
        }
        #pragma unroll
        for (int i = 0; i < RM; i++)
            #pragma unroll
            for (int j = 0; j < 4; j++) {
                acc[i][j] = __builtin_amdgcn_mfma_f32_16x16x32_bf16(am[i], bh[j], acc[i][j], 0, 0, 0);
                acc[i][j] = __builtin_amdgcn_mfma_f32_16x16x32_bf16(ah[i], bm_[j], acc[i][j], 0, 0, 0);
                acc[i][j] = __builtin_amdgcn_mfma_f32_16x16x32_bf16(ah[i], bh[j], acc[i][j], 0, 0, 0);
            }
        __syncthreads();
    }

    #pragma unroll
    for (int i = 0; i < RM; i++) {
        #pragma unroll
        for (int j = 0; j < 4; j++) {
            const long col = bn + wc * 64 + j * 16 + fr;
            const float bv = bias ? bias[col] : 0.f;
            #pragma unroll
            for (int r = 0; r < 4; r++) {
                const long row = bm + wr * (BMT / 2) + i * 16 + fq * 4 + r;
                float v = acc[i][j][r] * alpha + bv;
                if (RELU) v = fmaxf(v, 0.f);
                const long idx = TRANS ? (col * (long)ldc + row) : (row * (long)ldc + col);
                if (HILO) {
                    bf16 hh = (bf16)v;
                    Chi[idx] = hh;
                    Clo[idx] = (bf16)(v - (float)hh);
                } else {
                    C[idx] = v;
                }
            }
        }
    }
}

// ---------------------------------------------------------------- bf16x3 GEMM, pre-converted B (f32 A) -- v10 tier
template<int BMT, bool RELU>
__global__ __launch_bounds__(256, 2)
void gemm3p(const float* __restrict__ A,
            const bf16* __restrict__ Bph, const bf16* __restrict__ Bpl,
            const float* __restrict__ bias, float* __restrict__ C,
            int K, int lda, int ldb, int ldc)
{
    constexpr int BN = 128, TK = 32;
    constexpr int RM = BMT / 32;
    __shared__ __align__(16) bf16 Ah[BMT * TK];
    __shared__ __align__(16) bf16 Al[BMT * TK];
    __shared__ __align__(16) bf16 Bh[BN * TK];
    __shared__ __align__(16) bf16 Bl[BN * TK];

    const int tid  = threadIdx.x;
    const int wave = tid >> 6, lane = tid & 63;
    const int wr = wave >> 1, wc = wave & 1;
    const long bm = (long)blockIdx.y * BMT;
    const long bn = (long)blockIdx.x * BN;
    const int fr = lane & 15, fq = lane >> 4;

    f32x4v acc[RM][4] = {};

    for (int k0 = 0; k0 < K; k0 += TK) {
        #pragma unroll
        for (int it = 0; it < BMT / 64; it++) {
            const int c = it * 256 + tid;
            const int r = c >> 2, k8 = c & 3;
            const float* src = A + (bm + r) * (long)lda + k0 + k8 * 8;
            float4 f0 = ((const float4*)src)[0], f1 = ((const float4*)src)[1];
            float v[8] = {f0.x, f0.y, f0.z, f0.w, f1.x, f1.y, f1.z, f1.w};
            bf16x8 hh, ll; cvt8(v, hh, ll);
            *(bf16x8*)&Ah[r * TK + k8 * 8] = hh;
            *(bf16x8*)&Al[r * TK + k8 * 8] = ll;
        }
        #pragma unroll
        for (int it = 0; it < 2; it++) {
            const int c = it * 256 + tid;
            const int r = c >> 2, k8 = c & 3;
            const long bo = (bn + r) * (long)ldb + k0 + k8 * 8;
            *(uint4*)&Bh[r * TK + k8 * 8] = *(const uint4*)&Bph[bo];
            *(uint4*)&Bl[r * TK + k8 * 8] = *(const uint4*)&Bpl[bo];
        }
        __syncthreads();

        bf16x8 ah[RM], am[RM], bh[4], bm_[4];
        #pragma unroll
        for (int i = 0; i < RM; i++) {
            const int r = (wr * (BMT / 2) + i * 16 + fr) * TK + fq * 8;
            ah[i] = *(const bf16x8*)&Ah[r];
            am[i] = *(const bf16x8*)&Al[r];
        }
        #pragma unroll
        for (int j = 0; j < 4; j++) {
            const int r = (wc * 64 + j * 16 + fr) * TK + fq * 8;
            bh[j] = *(const bf16x8*)&Bh[r];
            bm_[j] = *(const bf16x8*)&Bl[r];
        }
        #pragma unroll
        for (int i = 0; i < RM; i++)
            #pragma unroll
            for (int j = 0; j < 4; j++) {
                acc[i][j] = __builtin_amdgcn_mfma_f32_16x16x32_bf16(am[i], bh[j], acc[i][j], 0, 0, 0);
                acc[i][j] = __builtin_amdgcn_mfma_f32_16x16x32_bf16(ah[i], bm_[j], acc[i][j], 0, 0, 0);
                acc[i][j] = __builtin_amdgcn_mfma_f32_16x16x32_bf16(ah[i], bh[j], acc[i][j], 0, 0, 0);
            }
        __syncthreads();
    }

    #pragma unroll
    for (int i = 0; i < RM; i++) {
        #pragma unroll
        for (int j = 0; j < 4; j++) {
            const long col = bn + wc * 64 + j * 16 + fr;
            const float bv = bias ? bias[col] : 0.f;
            #pragma unroll
            for (int r = 0; r < 4; r++) {
                const long row = bm + wr * (BMT / 2) + i * 16 + fq * 4 + r;
                float v = acc[i][j][r] + bv;
                if (RELU) v = fmaxf(v, 0.f);
                C[row * (long)ldc + col] = v;
            }
        }
    }
}

// ---------------------------------------------------------------- bf16x3 GEMM, pre-converted A AND B (hi/lo), optional hilo out
template<int BMT, bool RELU, bool OUTH>
__global__ __launch_bounds__(256, 2)
void gemm3q(const bf16* __restrict__ Agh, const bf16* __restrict__ Agl,
            const bf16* __restrict__ Bph, const bf16* __restrict__ Bpl,
            const float* __restrict__ bias, float* __restrict__ C,
            bf16* __restrict__ Oh, bf16* __restrict__ Ol,
            int K, int lda, int ldb, int ldc)
{
    constexpr int BN = 128, TK = 32;
    constexpr int RM = BMT / 32;
    __shared__ __align__(16) bf16 Ah[BMT * TK];
    __shared__ __align__(16) bf16 Al[BMT * TK];
    __shared__ __align__(16) bf16 Bh[BN * TK];
    __shared__ __align__(16) bf16 Bl[BN * TK];

    const int tid  = threadIdx.x;
    const int wave = tid >> 6, lane = tid & 63;
    const int wr = wave >> 1, wc = wave & 1;
    const long bm = (long)blockIdx.y * BMT;
    const long bn = (long)blockIdx.x * BN;
    const int fr = lane & 15, fq = lane >> 4;

    f32x4v acc[RM][4] = {};

    for (int k0 = 0; k0 < K; k0 += TK) {
        #pragma unroll
        for (int it = 0; it < (BMT + 63) / 64; it++) {
            const int c = it * 256 + tid;
            const int r = c >> 2, k8 = c & 3;
            const long ao = (bm + r) * (long)lda + k0 + k8 * 8;
            *(uint4*)&Ah[r * TK + k8 * 8] = *(const uint4*)&Agh[ao];
            *(uint4*)&Al[r * TK + k8 * 8] = *(const uint4*)&Agl[ao];
        }
        #pragma unroll
        for (int it = 0; it < 2; it++) {
            const int c = it * 256 + tid;
            const int r = c >> 2, k8 = c & 3;
            const long bo = (bn + r) * (long)ldb + k0 + k8 * 8;
            *(uint4*)&Bh[r * TK + k8 * 8] = *(const uint4*)&Bph[bo];
            *(uint4*)&Bl[r * TK + k8 * 8] = *(const uint4*)&Bpl[bo];
        }
        __syncthreads();

        bf16x8 ah[RM], am[RM], bh[4], bm_[4];
        #pragma unroll
        for (int i = 0; i < RM; i++) {
            const int r = (wr * (BMT / 2) + i * 16 + fr) * TK + fq * 8;
            ah[i] = *(const bf16x8*)&Ah[r];
            am[i] = *(const bf16x8*)&Al[r];
        }
        #pragma unroll
        for (int j = 0; j < 4; j++) {
            const int r = (wc * 64 + j * 16 + fr) * TK + fq * 8;
            bh[j] = *(const bf16x8*)&Bh[r];
            bm_[j] = *(const bf16x8*)&Bl[r];
        }
        #pragma unroll
        for (int i = 0; i < RM; i++)
            #pragma unroll
            for (int j = 0; j < 4; j++) {
                acc[i][j] = __builtin_amdgcn_mfma_f32_16x16x32_bf16(am[i], bh[j], acc[i][j], 0, 0, 0);
                acc[i][j] = __builtin_amdgcn_mfma_f32_16x16x32_bf16(ah[i], bm_[j], acc[i][j], 0, 0, 0);
                acc[i][j] = __builtin_amdgcn_mfma_f32_16x16x32_bf16(ah[i], bh[j], acc[i][j], 0, 0, 0);
            }
        __syncthreads();
    }

    #pragma unroll
    for (int i = 0; i < RM; i++) {
        #pragma unroll
        for (int j = 0; j < 4; j++) {
            const long col = bn + wc * 64 + j * 16 + fr;
            const float bv = bias ? bias[col] : 0.f;
            #pragma unroll
            for (int r = 0; r < 4; r++) {
                const long row = bm + wr * (BMT / 2) + i * 16 + fq * 4 + r;
                float v = acc[i][j][r] + bv;
                if (RELU) v = fmaxf(v, 0.f);
                const long idx = row * (long)ldc + col;
                C[idx] = v;
                if (OUTH) {
                    const bf16 hh = (bf16)v;
                    Oh[idx] = hh;
                    Ol[idx] = (bf16)(v - (float)hh);
                }
            }
        }
    }
}

// ---------------------------------------------------------------- bf16x3 GEMM, small-tile variant (hilo A+B); FOUT gates f32 store
template<bool RELU, bool OUTH, bool FOUT>
__global__ __launch_bounds__(128, 4)
void gemm3s(const bf16* __restrict__ Agh, const bf16* __restrict__ Agl,
            const bf16* __restrict__ Bph, const bf16* __restrict__ Bpl,
            const float* __restrict__ bias, float* __restrict__ C,
            bf16* __restrict__ Oh, bf16* __restrict__ Ol,
            int K, int lda, int ldb, int ldc)
{
    constexpr int BM = 32, BN = 64, TK = 32;
    __shared__ __align__(16) bf16 Ah[BM * TK];
    __shared__ __align__(16) bf16 Al[BM * TK];
    __shared__ __align__(16) bf16 Bh[BN * TK];
    __shared__ __align__(16) bf16 Bl[BN * TK];

    const int tid  = threadIdx.x;                 // 0..127
    const int wave = tid >> 6, lane = tid & 63;
    const int fr = lane & 15, fq = lane >> 4;
    const long bm = (long)blockIdx.y * BM;
    const long bn = (long)blockIdx.x * BN;

    f32x4v acc[4] = {};

    for (int k0 = 0; k0 < K; k0 += TK) {
        {
            const int r = tid >> 2, k8 = tid & 3;
            const long ao = (bm + r) * (long)lda + k0 + k8 * 8;
            *(uint4*)&Ah[r * TK + k8 * 8] = *(const uint4*)&Agh[ao];
            *(uint4*)&Al[r * TK + k8 * 8] = *(const uint4*)&Agl[ao];
        }
        #pragma unroll
        for (int it = 0; it < 2; it++) {
            const int c = it * 128 + tid;
            const int r = c >> 2, k8 = c & 3;
            const long bo = (bn + r) * (long)ldb + k0 + k8 * 8;
            *(uint4*)&Bh[r * TK + k8 * 8] = *(const uint4*)&Bph[bo];
            *(uint4*)&Bl[r * TK + k8 * 8] = *(const uint4*)&Bpl[bo];
        }
        __syncthreads();

        bf16x8 ah, am, bh[4], bm_[4];
        {
            const int r = (wave * 16 + fr) * TK + fq * 8;
            ah = *(const bf16x8*)&Ah[r];
            am = *(const bf16x8*)&Al[r];
        }
        #pragma unroll
        for (int j = 0; j < 4; j++) {
            const int r = (j * 16 + fr) * TK + fq * 8;
            bh[j]  = *(const bf16x8*)&Bh[r];
            bm_[j] = *(const bf16x8*)&Bl[r];
        }
        #pragma unroll
        for (int j = 0; j < 4; j++) {
            acc[j] = __builtin_amdgcn_mfma_f32_16x16x32_bf16(am, bh[j], acc[j], 0, 0, 0);
            acc[j] = __builtin_amdgcn_mfma_f32_16x16x32_bf16(ah, bm_[j], acc[j], 0, 0, 0);
            acc[j] = __builtin_amdgcn_mfma_f32_16x16x32_bf16(ah, bh[j], acc[j], 0, 0, 0);
        }
        __syncthreads();
    }

    #pragma unroll
    for (int j = 0; j < 4; j++) {
        const long col = bn + j * 16 + fr;
        const float bv = bias ? bias[col] : 0.f;
        #pragma unroll
        for (int r = 0; r < 4; r++) {
            const long row = bm + wave * 16 + fq * 4 + r;
            float v = acc[j][r] + bv;
            if (RELU) v = fmaxf(v, 0.f);
            const long idx = row * (long)ldc + col;
            if (FOUT) C[idx] = v;
            if (OUTH) {
                const bf16 hh = (bf16)v;
                Oh[idx] = hh;
                Ol[idx] = (bf16)(v - (float)hh);
            }
        }
    }
}

// ---------------------------------------------------------------- fused QKV projection (legacy f32 A+W)
__global__ __launch_bounds__(256, 2)
void qkv_gemm(const float* __restrict__ X,
              const float* __restrict__ Wq, const float* __restrict__ Wk, const float* __restrict__ Wv,
              const float* __restrict__ Bq, const float* __restrict__ Bk, const float* __restrict__ Bv,
              float* __restrict__ Qo, bf16* __restrict__ Khi, bf16* __restrict__ Klo,
              bf16* __restrict__ Vthi, bf16* __restrict__ Vtlo)
{
    constexpr int TK = 32, D = 512, N = 4096;
    __shared__ __align__(16) bf16 Ah[64 * TK];
    __shared__ __align__(16) bf16 Al[64 * TK];
    __shared__ __align__(16) bf16 Bh[128 * TK];
    __shared__ __align__(16) bf16 Bl[128 * TK];

    const int tid  = threadIdx.x;
    const int wave = tid >> 6, lane = tid & 63;
    const int wr = wave >> 1, wc = wave & 1;
    const int sel = blockIdx.x >> 2, wcol0 = (blockIdx.x & 3) * 128;
    const long bm = (long)blockIdx.y * 64;
    const int fr = lane & 15, fq = lane >> 4;

    const float* W  = sel == 0 ? Wq : (sel == 1 ? Wk : Wv);
    const float* Bb = sel == 0 ? Bq : (sel == 1 ? Bk : Bv);

    f32x4v acc[2][4] = {};

    for (int k0 = 0; k0 < D; k0 += TK) {
        {
            const int r = tid >> 2, k8 = tid & 3;
            const float* src = X + (bm + r) * (long)D + k0 + k8 * 8;
            float4 f0 = ((const float4*)src)[0], f1 = ((const float4*)src)[1];
            float v[8] = {f0.x, f0.y, f0.z, f0.w, f1.x, f1.y, f1.z, f1.w};
            bf16x8 hh, ll; cvt8(v, hh, ll);
            *(bf16x8*)&Ah[r * TK + k8 * 8] = hh;
            *(bf16x8*)&Al[r * TK + k8 * 8] = ll;
        }
        {
            const int col = tid & 127, bkh = (tid >> 7) * 16;
            const float* src = W + (long)(k0 + bkh) * D + wcol0 + col;
            float v[16];
            #pragma unroll
            for (int kk = 0; kk < 16; kk++) v[kk] = src[(long)kk * D];
            bf16x8 h0, l0, h1, l1; cvt8(v, h0, l0); cvt8(v + 8, h1, l1);
            bf16* hd = &Bh[col * TK + bkh];
            bf16* ld_ = &Bl[col * TK + bkh];
            ((bf16x8*)hd)[0] = h0; ((bf16x8*)hd)[1] = h1;
            ((bf16x8*)ld_)[0] = l0; ((bf16x8*)ld_)[1] = l1;
        }
        __syncthreads();

        bf16x8 ah[2], am[2], bh[4], bm_[4];
        #pragma unroll
        for (int i = 0; i < 2; i++) {
            const int r = (wr * 32 + i * 16 + fr) * TK + fq * 8;
            ah[i] = *(const bf16x8*)&Ah[r];
            am[i] = *(const bf16x8*)&Al[r];
        }
        #pragma unroll
        for (int j = 0; j < 4; j++) {
            const int r = (wc * 64 + j * 16 + fr) * TK + fq * 8;
            bh[j] = *(const bf16x8*)&Bh[r];
            bm_[j] = *(const bf16x8*)&Bl[r];
        }
        #pragma unroll
        for (int i = 0; i < 2; i++)
            #pragma unroll
            for (int j = 0; j < 4; j++) {
                acc[i][j] = __builtin_amdgcn_mfma_f32_16x16x32_bf16(am[i], bh[j], acc[i][j], 0, 0, 0);
                acc[i][j] = __builtin_amdgcn_mfma_f32_16x16x32_bf16(ah[i], bm_[j], acc[i][j], 0, 0, 0);
                acc[i][j] = __builtin_amdgcn_mfma_f32_16x16x32_bf16(ah[i], bh[j], acc[i][j], 0, 0, 0);
            }
        __syncthreads();
    }

    #pragma unroll
    for (int i = 0; i < 2; i++) {
        #pragma unroll
        for (int j = 0; j < 4; j++) {
            const int col = wc * 64 + j * 16 + fr;
            const float bv = Bb[wcol0 + col];
            #pragma unroll
            for (int r = 0; r < 4; r++) {
                const long row = bm + wr * 32 + i * 16 + fq * 4 + r;
                const float v = acc[i][j][r] + bv;
                if (sel == 0) {
                    Qo[row * D + wcol0 + col] = v;
                } else {
                    const bf16 hh = (bf16)v;
                    const bf16 ll = (bf16)(v - (float)hh);
                    const long idx = (sel == 1) ? (row * (long)D + wcol0 + col)
                                                : ((long)(wcol0 + col) * N + row);
                    if (sel == 1) { Khi[idx] = hh; Klo[idx] = ll; }
                    else          { Vthi[idx] = hh; Vtlo[idx] = ll; }
                }
            }
        }
    }
}

// ---------------------------------------------------------------- fused QKV, pre-converted W^T, f32 X (v10 tier)
__global__ __launch_bounds__(256, 2)
void qkv_gemmp(const float* __restrict__ X,
               const bf16* __restrict__ Wqh, const bf16* __restrict__ Wql,
               const bf16* __restrict__ Wkh, const bf16* __restrict__ Wkl,
               const bf16* __restrict__ Wvh, const bf16* __restrict__ Wvl,
               const float* __restrict__ Bq, const float* __restrict__ Bk, const float* __restrict__ Bv,
               float* __restrict__ Qo, bf16* __restrict__ Khi, bf16* __restrict__ Klo,
               bf16* __restrict__ Vthi, bf16* __restrict__ Vtlo)
{
    constexpr int TK = 32, D = 512, N = 4096;
    __shared__ __align__(16) bf16 Ah[64 * TK];
    __shared__ __align__(16) bf16 Al[64 * TK];
    __shared__ __align__(16) bf16 Bh[128 * TK];
    __shared__ __align__(16) bf16 Bl[128 * TK];

    const int tid  = threadIdx.x;
    const int wave = tid >> 6, lane = tid & 63;
    const int wr = wave >> 1, wc = wave & 1;
    const int sel = blockIdx.x >> 2, wcol0 = (blockIdx.x & 3) * 128;
    const long bm = (long)blockIdx.y * 64;
    const int fr = lane & 15, fq = lane >> 4;

    const bf16* Wh = sel == 0 ? Wqh : (sel == 1 ? Wkh : Wvh);
    const bf16* Wl = sel == 0 ? Wql : (sel == 1 ? Wkl : Wvl);
    const float* Bb = sel == 0 ? Bq : (sel == 1 ? Bk : Bv);

    f32x4v acc[2][4] = {};

    for (int k0 = 0; k0 < D; k0 += TK) {
        {
            const int r = tid >> 2, k8 = tid & 3;
            const float* src = X + (bm + r) * (long)D + k0 + k8 * 8;
            float4 f0 = ((const float4*)src)[0], f1 = ((const float4*)src)[1];
            float v[8] = {f0.x, f0.y, f0.z, f0.w, f1.x, f1.y, f1.z, f1.w};
            bf16x8 hh, ll; cvt8(v, hh, ll);
            *(bf16x8*)&Ah[r * TK + k8 * 8] = hh;
            *(bf16x8*)&Al[r * TK + k8 * 8] = ll;
        }
        #pragma unroll
        for (int it = 0; it < 2; it++) {
            const int c = it * 256 + tid;
            const int r = c >> 2, k8 = c & 3;
            const long bo = (long)(wcol0 + r) * D + k0 + k8 * 8;
            *(uint4*)&Bh[r * TK + k8 * 8] = *(const uint4*)&Wh[bo];
            *(uint4*)&Bl[r * TK + k8 * 8] = *(const uint4*)&Wl[bo];
        }
        __syncthreads();

        bf16x8 ah[2], am[2], bh[4], bm_[4];
        #pragma unroll
        for (int i = 0; i < 2; i++) {
            const int r = (wr * 32 + i * 16 + fr) * TK + fq * 8;
            ah[i] = *(const bf16x8*)&Ah[r];
            am[i] = *(const bf16x8*)&Al[r];
        }
        #pragma unroll
        for (int j = 0; j < 4; j++) {
            const int r = (wc * 64 + j * 16 + fr) * TK + fq * 8;
            bh[j] = *(const bf16x8*)&Bh[r];
            bm_[j] = *(const bf16x8*)&Bl[r];
        }
        #pragma unroll
        for (int i = 0; i < 2; i++)
            #pragma unroll
            for (int j = 0; j < 4; j++) {
                acc[i][j] = __builtin_amdgcn_mfma_f32_16x16x32_bf16(am[i], bh[j], acc[i][j], 0, 0, 0);
                acc[i][j] = __builtin_amdgcn_mfma_f32_16x16x32_bf16(ah[i], bm_[j], acc[i][j], 0, 0, 0);
                acc[i][j] = __builtin_amdgcn_mfma_f32_16x16x32_bf16(ah[i], bh[j], acc[i][j], 0, 0, 0);
            }
        __syncthreads();
    }

    #pragma unroll
    for (int i = 0; i < 2; i++) {
        #pragma unroll
        for (int j = 0; j < 4; j++) {
            const int col = wc * 64 + j * 16 + fr;
            const float bv = Bb[wcol0 + col];
            #pragma unroll
            for (int r = 0; r < 4; r++) {
                const long row = bm + wr * 32 + i * 16 + fq * 4 + r;
                const float v = acc[i][j][r] + bv;
                if (sel == 0) {
                    Qo[row * D + wcol0 + col] = v;
                } else {
                    const bf16 hh = (bf16)v;
                    const bf16 ll = (bf16)(v - (float)hh);
                    const long idx = (sel == 1) ? (row * (long)D + wcol0 + col)
                                                : ((long)(wcol0 + col) * N + row);
                    if (sel == 1) { Khi[idx] = hh; Klo[idx] = ll; }
                    else          { Vthi[idx] = hh; Vtlo[idx] = ll; }
                }
            }
        }
    }
}

// ---------------------------------------------------------------- fused QKV, pre-converted W^T AND hilo X (v11 tier)
__global__ __launch_bounds__(256, 2)
void qkv_gemmq(const bf16* __restrict__ Xh, const bf16* __restrict__ Xl,
               const bf16* __restrict__ Wqh, const bf16* __restrict__ Wql,
               const bf16* __restrict__ Wkh, const bf16* __restrict__ Wkl,
               const bf16* __restrict__ Wvh, const bf16* __restrict__ Wvl,
               const float* __restrict__ Bq, const float* __restrict__ Bk, const float* __restrict__ Bv,
               float* __restrict__ Qo, bf16* __restrict__ Khi, bf16* __restrict__ Klo,
               bf16* __restrict__ Vthi, bf16* __restrict__ Vtlo)
{
    constexpr int TK = 32, D = 512, N = 4096;
    __shared__ __align__(16) bf16 Ah[64 * TK];
    __shared__ __align__(16) bf16 Al[64 * TK];
    __shared__ __align__(16) bf16 Bh[128 * TK];
    __shared__ __align__(16) bf16 Bl[128 * TK];

    const int tid  = threadIdx.x;
    const int wave = tid >> 6, lane = tid & 63;
    const int wr = wave >> 1, wc = wave & 1;
    const int sel = blockIdx.x >> 2, wcol0 = (blockIdx.x & 3) * 128;
    const long bm = (long)blockIdx.y * 64;
    const int fr = lane & 15, fq = lane >> 4;

    const bf16* Wh = sel == 0 ? Wqh : (sel == 1 ? Wkh : Wvh);
    const bf16* Wl = sel == 0 ? Wql : (sel == 1 ? Wkl : Wvl);
    const float* Bb = sel == 0 ? Bq : (sel == 1 ? Bk : Bv);

    f32x4v acc[2][4] = {};

    for (int k0 = 0; k0 < D; k0 += TK) {
        {
            const int r = tid >> 2, k8 = tid & 3;
            const long ao = (bm + r) * (long)D + k0 + k8 * 8;
            *(uint4*)&Ah[r * TK + k8 * 8] = *(const uint4*)&Xh[ao];
            *(uint4*)&Al[r * TK + k8 * 8] = *(const uint4*)&Xl[ao];
        }
        #pragma unroll
        for (int it = 0; it < 2; it++) {
            const int c = it * 256 + tid;
            const int r = c >> 2, k8 = c & 3;
            const long bo = (long)(wcol0 + r) * D + k0 + k8 * 8;
            *(uint4*)&Bh[r * TK + k8 * 8] = *(const uint4*)&Wh[bo];
            *(uint4*)&Bl[r * TK + k8 * 8] = *(const uint4*)&Wl[bo];
        }
        __syncthreads();

        bf16x8 ah[2], am[2], bh[4], bm_[4];
        #pragma unroll
        for (int i = 0; i < 2; i++) {
            const int r = (wr * 32 + i * 16 + fr) * TK + fq * 8;
            ah[i] = *(const bf16x8*)&Ah[r];
            am[i] = *(const bf16x8*)&Al[r];
        }
        #pragma unroll
        for (int j = 0; j < 4; j++) {
            const int r = (wc * 64 + j * 16 + fr) * TK + fq * 8;
            bh[j] = *(const bf16x8*)&Bh[r];
            bm_[j] = *(const bf16x8*)&Bl[r];
        }
        #pragma unroll
        for (int i = 0; i < 2; i++)
            #pragma unroll
            for (int j = 0; j < 4; j++) {
                acc[i][j] = __builtin_amdgcn_mfma_f32_16x16x32_bf16(am[i], bh[j], acc[i][j], 0, 0, 0);
                acc[i][j] = __builtin_amdgcn_mfma_f32_16x16x32_bf16(ah[i], bm_[j], acc[i][j], 0, 0, 0);
                acc[i][j] = __builtin_amdgcn_mfma_f32_16x16x32_bf16(ah[i], bh[j], acc[i][j], 0, 0, 0);
            }
        __syncthreads();
    }

    #pragma unroll
    for (int i = 0; i < 2; i++) {
        #pragma unroll
        for (int j = 0; j < 4; j++) {
            const int col = wc * 64 + j * 16 + fr;
            const float bv = Bb[wcol0 + col];
            #pragma unroll
            for (int r = 0; r < 4; r++) {
                const long row = bm + wr * 32 + i * 16 + fq * 4 + r;
                const float v = acc[i][j][r] + bv;
                if (sel == 0) {
                    Qo[row * D + wcol0 + col] = v;
                } else {
                    const bf16 hh = (bf16)v;
                    const bf16 ll = (bf16)(v - (float)hh);
                    const long idx = (sel == 1) ? (row * (long)D + wcol0 + col)
                                                : ((long)(wcol0 + col) * N + row);
                    if (sel == 1) { Khi[idx] = hh; Klo[idx] = ll; }
                    else          { Vthi[idx] = hh; Vtlo[idx] = ll; }
                }
            }
        }
    }
}

// ---------------------------------------------------------------- weight pre-convert + transpose
struct W14 { const float* w[14]; };

__global__ void convert_weights(W14 p, bf16* __restrict__ wsb)
{
    const int z = blockIdx.z;
    const int tid = threadIdx.x;
    int wi, n0, N_;
    if (z < 13) { wi = z; n0 = blockIdx.y * 32; N_ = 512; }
    else        { wi = 13; n0 = (z - 13) * 512 + blockIdx.y * 32; N_ = 4096; }
    const int k0 = blockIdx.x * 32;
    const float* W = p.w[wi];
    const long base = (wi < 13) ? (long)wi * 524288 : 6815744L;
    const long hsz  = (wi < 13) ? 262144L : 2097152L;
    bf16* hi = wsb + base;
    bf16* lo = wsb + base + hsz;

    __shared__ float tile[32][33];
    #pragma unroll
    for (int i = 0; i < 4; i++) {
        const int idx = i * 256 + tid;
        const int r = idx >> 5, c = idx & 31;
        tile[r][c] = W[(long)(k0 + r) * N_ + n0 + c];
    }
    __syncthreads();
    #pragma unroll
    for (int i = 0; i < 4; i++) {
        const int idx = i * 256 + tid;
        const int r = idx >> 5, c = idx & 31;
        const float v = tile[c][r];
        const bf16 h = (bf16)v;
        const long o = (long)(n0 + r) * 512 + k0 + c;
        hi[o] = h;
        lo[o] = (bf16)(v - (float)h);
    }
}

// ---------------------------------------------------------------- f32 activation -> hilo split (elementwise)
__global__ void convert_x(const float* __restrict__ x,
                          bf16* __restrict__ hi, bf16* __restrict__ lo)
{
    const long i = ((long)blockIdx.x * 256 + threadIdx.x) * 8;
    float4 f0 = ((const float4*)(x + i))[0], f1 = ((const float4*)(x + i))[1];
    float v[8] = {f0.x, f0.y, f0.z, f0.w, f1.x, f1.y, f1.z, f1.w};
    bf16x8 hh, ll; cvt8(v, hh, ll);
    *(bf16x8*)&hi[i] = hh;
    *(bf16x8*)&lo[i] = ll;
}

// ---------------------------------------------------------------- fused flash attention v15 (template NS = KV splits)
// NS=8: grid (64,4,8)=2048 blocks -> 5 resident blocks/CU (LDS-limited) vs 4
// at NS=4 (grid-capped). Partials f32; s<4 -> OpA, s>=4 -> OpB. Per-block
// math identical to v13 (defer-rescale kept).
template<int NS>
__global__ __launch_bounds__(128, 2)
void flash_attn(const float* __restrict__ Q,
                const bf16* __restrict__ Khi, const bf16* __restrict__ Klo,
                const bf16* __restrict__ Vthi, const bf16* __restrict__ Vtlo,
                float* __restrict__ OpA, float* __restrict__ OpB, float* __restrict__ ml)
{
    constexpr int N = 4096, D = 512, TKV = 32;
    constexpr int SPAN = N / NS;
    constexpr int NT = SPAN / TKV;
    constexpr float TS = 0.12751791f;   // (1/sqrt(128)) * log2(e)

    __shared__ __align__(16) bf16 smem[16384];   // 32 KB
    bf16* Kh = smem;
    bf16* Kl = smem + 4096;
    bf16* Vh = smem + 8192;
    bf16* Vl = smem + 12288;

    const int tid = threadIdx.x;                 // 0..127
    const int wave = tid >> 6, lane = tid & 63;
    const int fr = lane & 15, fq = lane >> 4;
    const int qt = blockIdx.x, h = blockIdx.y, s = blockIdx.z;
    const long q0 = (long)qt * 64;

    const int kn = tid >> 4, kk8 = tid & 15;
    const int vd = tid >> 2, vk8 = tid & 3;

    bf16x8 qh[2][4], ql[2][4];
    #pragma unroll
    for (int rg = 0; rg < 2; rg++)
        #pragma unroll
        for (int kt = 0; kt < 4; kt++) {
            const float* src = Q + (q0 + wave * 32 + rg * 16 + fr) * D + h * 128 + kt * 32 + fq * 8;
            float4 f0 = ((const float4*)src)[0], f1 = ((const float4*)src)[1];
            float v[8] = {f0.x, f0.y, f0.z, f0.w, f1.x, f1.y, f1.z, f1.w};
            cvt8(v, qh[rg][kt], ql[rg][kt]);
        }

    f32x4v o[2][8] = {};
    float m_run[2] = {-1e30f, -1e30f}, l_run[2] = {0.f, 0.f};

    const int j0base = s * SPAN;

    #pragma unroll 1
    for (int jt = 0; jt < NT; jt++) {
        const int j0 = j0base + jt * TKV;

        #pragma unroll
        for (int i = 0; i < 4; i++) {
            const int n = kn + 8 * i;
            const long kg = (long)(j0 + n) * D + h * 128 + kk8 * 8;
            const int ko = n * 128 + ((kk8 ^ (n & 15)) << 3);
            *(uint4*)&Kh[ko] = *(const uint4*)&Khi[kg];
            *(uint4*)&Kl[ko] = *(const uint4*)&Klo[kg];
            const int d = vd + 32 * i;
            const long vg = (long)(h * 128 + d) * N + j0 + vk8 * 8;
            const int vo = d * 32 + ((vk8 ^ ((d >> 2) & 3)) << 3);
            *(uint4*)&Vh[vo] = *(const uint4*)&Vthi[vg];
            *(uint4*)&Vl[vo] = *(const uint4*)&Vtlo[vg];
        }
        __syncthreads();

        f32x4v sacc[2][2] = {};
        #pragma unroll
        for (int jb = 0; jb < 2; jb++) {
            bf16x8 kh[4], km[4];
            #pragma unroll
            for (int kt = 0; kt < 4; kt++) {
                const int off = (jb * 16 + fr) * 128 + (((kt * 4 + fq) ^ fr) << 3);
                kh[kt] = *(const bf16x8*)&Kh[off];
                km[kt] = *(const bf16x8*)&Kl[off];
            }
            __builtin_amdgcn_s_setprio(1);
            #pragma unroll
            for (int kt = 0; kt < 4; kt++)
                #pragma unroll
                for (int rg = 0; rg < 2; rg++) {
                    sacc[rg][jb] = __builtin_amdgcn_mfma_f32_16x16x32_bf16(km[kt], qh[rg][kt], sacc[rg][jb], 0, 0, 0);
                    sacc[rg][jb] = __builtin_amdgcn_mfma_f32_16x16x32_bf16(kh[kt], ql[rg][kt], sacc[rg][jb], 0, 0, 0);
                    sacc[rg][jb] = __builtin_amdgcn_mfma_f32_16x16x32_bf16(kh[kt], qh[rg][kt], sacc[rg][jb], 0, 0, 0);
                }
            __builtin_amdgcn_s_setprio(0);
        }

        bf16x8 ph[2], pl[2];
        float alpha[2];
        bool upd[2];
        #pragma unroll
        for (int rg = 0; rg < 2; rg++) {
            float t[2][4];
            float mloc = -1e30f;
            #pragma unroll
            for (int jb = 0; jb < 2; jb++)
                #pragma unroll
                for (int r = 0; r < 4; r++) {
                    t[jb][r] = sacc[rg][jb][r] * TS;
                    mloc = fmaxf(mloc, t[jb][r]);
                }
            mloc = fmaxf(mloc, __shfl_xor(mloc, 16));
            mloc = fmaxf(mloc, __shfl_xor(mloc, 32));
            upd[rg] = !__all(mloc <= m_run[rg]);
            float mn;
            if (upd[rg]) {
                mn = fmaxf(m_run[rg], mloc);
                alpha[rg] = exp2f(m_run[rg] - mn);
                m_run[rg] = mn;
            } else {
                mn = m_run[rg];
                alpha[rg] = 1.f;
            }

            float p[2][4];
            float rs = 0.f;
            #pragma unroll
            for (int jb = 0; jb < 2; jb++)
                #pragma unroll
                for (int r = 0; r < 4; r++) {
                    p[jb][r] = exp2f(t[jb][r] - mn);
                    rs += p[jb][r];
                }
            rs += __shfl_xor(rs, 16);
            rs += __shfl_xor(rs, 32);
            l_run[rg] = l_run[rg] * alpha[rg] + rs;

            unsigned int hp[2][2], lp[2][2];
            #pragma unroll
            for (int jb = 0; jb < 2; jb++)
                #pragma unroll
                for (int t2 = 0; t2 < 2; t2++) {
                    const float p0 = p[jb][2 * t2], p1 = p[jb][2 * t2 + 1];
                    const bf16 h0 = (bf16)p0, h1 = (bf16)p1;
                    const unsigned short u0 = __builtin_bit_cast(unsigned short, h0);
                    const unsigned short u1 = __builtin_bit_cast(unsigned short, h1);
                    hp[jb][t2] = (unsigned int)u0 | ((unsigned int)u1 << 16);
                    const bf16 g0 = (bf16)(p0 - (float)h0), g1 = (bf16)(p1 - (float)h1);
                    const unsigned short w0 = __builtin_bit_cast(unsigned short, g0);
                    const unsigned short w1 = __builtin_bit_cast(unsigned short, g1);
                    lp[jb][t2] = (unsigned int)w0 | ((unsigned int)w1 << 16);
                }

            uint4 PH, PL;
            {
                unsigned int phw[4], plw[4];
                #pragma unroll
                for (int w = 0; w < 4; w++) {
                    const int src = ((2 * (fq & 1) + (w >> 1)) << 4) + fr;
                    const unsigned int h0 = (unsigned int)__shfl((int)hp[0][w & 1], src);
                    const unsigned int h1 = (unsigned int)__shfl((int)hp[1][w & 1], src);
                    phw[w] = (fq >> 1) ? h1 : h0;
                    const unsigned int g0 = (unsigned int)__shfl((int)lp[0][w & 1], src);
                    const unsigned int g1 = (unsigned int)__shfl((int)lp[1][w & 1], src);
                    plw[w] = (fq >> 1) ? g1 : g0;
                }
                PH.x = phw[0]; PH.y = phw[1]; PH.z = phw[2]; PH.w = phw[3];
                PL.x = plw[0]; PL.y = plw[1]; PL.z = plw[2]; PL.w = plw[3];
            }
            ph[rg] = __builtin_bit_cast(bf16x8, PH);
            pl[rg] = __builtin_bit_cast(bf16x8, PL);
        }

        // ---- rescale O only when the running max changed (wave-uniform)
        #pragma unroll
        for (int rg = 0; rg < 2; rg++) {
            if (upd[rg]) {
                float alr[4];
                #pragma unroll
                for (int r = 0; r < 4; r++) alr[r] = __shfl(alpha[rg], fq * 4 + r);
                #pragma unroll
                for (int jbo = 0; jbo < 8; jbo++)
                    #pragma unroll
                    for (int r = 0; r < 4; r++)
                        o[rg][jbo][r] *= alr[r];
            }
        }

        #pragma unroll
        for (int jbo = 0; jbo < 8; jbo++) {
            const int off = (jbo * 16 + fr) * 32 + ((fq ^ ((fr >> 2) & 3)) << 3);
            const bf16x8 vh_ = *(const bf16x8*)&Vh[off];
            const bf16x8 vl_ = *(const bf16x8*)&Vl[off];
            __builtin_amdgcn_s_setprio(1);
            #pragma unroll
            for (int rg = 0; rg < 2; rg++) {
                o[rg][jbo] = __builtin_amdgcn_mfma_f32_16x16x32_bf16(pl[rg], vh_, o[rg][jbo], 0, 0, 0);
                o[rg][jbo] = __builtin_amdgcn_mfma_f32_16x16x32_bf16(ph[rg], vl_, o[rg][jbo], 0, 0, 0);
                o[rg][jbo] = __builtin_amdgcn_mfma_f32_16x16x32_bf16(ph[rg], vh_, o[rg][jbo], 0, 0, 0);
            }
            __builtin_amdgcn_s_setprio(0);
        }
        __syncthreads();
    }

    // ---- store unnormalized partial O + (m, l)
    const long sidx = (long)((h * 64 + qt) * NS + s);
    float* ob;
    if (NS == 4 || s < 4) ob = OpA + (long)((h * 64 + qt) * 4 + (s & 3)) * 8192;
    else                  ob = OpB + (long)((h * 64 + qt) * 4 + (s - 4)) * 8192;
    #pragma unroll
    for (int rg = 0; rg < 2; rg++)
        #pragma unroll
        for (int jbo = 0; jbo < 8; jbo++)
            #pragma unroll
            for (int r = 0; r < 4; r++) {
                const int lrow = wave * 32 + rg * 16 + fq * 4 + r;
                ob[lrow * 128 + jbo * 16 + fr] = o[rg][jbo][r];
            }
    if (fq == 0) {
        #pragma unroll
        for (int rg = 0; rg < 2; rg++) {
            const int lrow = wave * 32 + rg * 16 + fr;
            ml[sidx * 128 + lrow]      = m_run[rg];
            ml[sidx * 128 + 64 + lrow] = l_run[rg];
        }
    }
}

// ---------------------------------------------------------------- merge NS KV-splits (exact); OUTH hilo / FOUT f32 gates
template<int NS, bool OUTH, bool FOUT>
__global__ void flash_merge_t(const float* __restrict__ OpA, const float* __restrict__ OpB,
                              const float* __restrict__ ml,
                              float* __restrict__ ctx, bf16* __restrict__ ch, bf16* __restrict__ cl)
{
    const int idx = blockIdx.x;            // h*64 + qt, 256 blocks
    const int h = idx >> 6, qt = idx & 63;
    const int tid = threadIdx.x;
    __shared__ float es[NS][64], il[64];
    if (tid < 64) {
        float m[NS], l[NS];
        float mx = -1e30f;
        #pragma unroll
        for (int s = 0; s < NS; s++) {
            m[s] = ml[(long)(idx * NS + s) * 128 + tid];
            l[s] = ml[(long)(idx * NS + s) * 128 + 64 + tid];
            mx = fmaxf(mx, m[s]);
        }
        float denom = 0.f;
        #pragma unroll
        for (int s = 0; s < NS; s++) {
            const float e = exp2f(m[s] - mx);
            es[s][tid] = e;
            denom += e * l[s];
        }
        il[tid] = 1.f / denom;
    }
    __syncthreads();
    #pragma unroll
    for (int i = 0; i < 32; i++) {
        const int e = tid + i * 256;
        const int row = e >> 7, col = e & 127;
        float v = 0.f;
        #pragma unroll
        for (int s = 0; s < NS; s++) {
            const float* src = (NS == 4 || s < 4)
                ? OpA + (long)(idx * 4 + (s & 3)) * 8192
                : OpB + (long)(idx * 4 + (s - 4)) * 8192;
            v += es[s][row] * src[e];
        }
        const float vv = v * il[row];
        const long cidx = (long)(qt * 64 + row) * 512 + h * 128 + col;
        if (FOUT) ctx[cidx] = vv;
        if (OUTH) {
            const bf16 hh = (bf16)vv;
            ch[cidx] = hh;
            cl[cidx] = (bf16)(vv - (float)hh);
        }
    }
}

// ---------------------------------------------------------------- residual + layernorm; OUTH hilo / FOUT f32 gates
template<bool OUTH, bool FOUT>
__global__ void add_ln_t(const float* __restrict__ a, const float* __restrict__ b,
                         const float* __restrict__ g, const float* __restrict__ be,
                         float* __restrict__ out, bf16* __restrict__ oh, bf16* __restrict__ ol)
{
    const long row = blockIdx.x;
    const int tid = threadIdx.x;
    const long base = row * 512L;
    float x0 = a[base + tid]       + b[base + tid];
    float x1 = a[base + tid + 256] + b[base + tid + 256];
    float s = block_reduce_sum256(x0 + x1);
    float mu = s * (1.f / 512.f);
    float d0 = x0 - mu, d1 = x1 - mu;
    float var = block_reduce_sum256(d0 * d0 + d1 * d1) * (1.f / 512.f);
    float invs = rsqrtf(var + 1e-6f);
    const float y0 = d0 * invs * g[tid]       + be[tid];
    const float y1 = d1 * invs * g[tid + 256] + be[tid + 256];
    if (FOUT) {
        out[base + tid]       = y0;
        out[base + tid + 256] = y1;
    }
    if (OUTH) {
        const bf16 h0 = (bf16)y0, h1 = (bf16)y1;
        oh[base + tid]       = h0;
        ol[base + tid]       = (bf16)(y0 - (float)h0);
        oh[base + tid + 256] = h1;
        ol[base + tid + 256] = (bf16)(y1 - (float)h1);
    }
}

// ---------------------------------------------------------------- normalize emb rows (legacy f32 out)
__global__ void normalize_emb(const float* __restrict__ emb, float* __restrict__ embn)
{
    const long row = blockIdx.x;
    const int tid = threadIdx.x;
    const long base = row * 512L;
    float a0 = emb[base + tid];
    float a1 = emb[base + tid + 256];
    float ss = block_reduce_sum256(a0 * a0 + a1 * a1);
    float sc = rsqrtf(fmaxf(ss, 1e-12f));
    embn[base + tid]       = a0 * sc;
    embn[base + tid + 256] = a1 * sc;
}

// ---------------------------------------------------------------- normalize emb rows -> bf16 hi/lo
__global__ void normalize_emb_p(const float* __restrict__ emb,
                                bf16* __restrict__ hi, bf16* __restrict__ lo)
{
    const long row = blockIdx.x;
    const int tid = threadIdx.x;
    const long base = row * 512L;
    float a0 = emb[base + tid];
    float a1 = emb[base + tid + 256];
    float ss = block_reduce_sum256(a0 * a0 + a1 * a1);
    float sc = rsqrtf(fmaxf(ss, 1e-12f));
    const float e0 = a0 * sc, e1 = a1 * sc;
    const bf16 h0 = (bf16)e0, h1 = (bf16)e1;
    hi[base + tid]       = h0;
    lo[base + tid]       = (bf16)(e0 - (float)h0);
    hi[base + tid + 256] = h1;
    lo[base + tid + 256] = (bf16)(e1 - (float)h1);
}

// ---------------------------------------------------------------- VQ select; optional hilo vq_feat out
template<bool OUTH>
__global__ void vq_select_t(float* __restrict__ sims, const float* __restrict__ emb,
                            float* __restrict__ vq_out, bf16* __restrict__ vh, bf16* __restrict__ vl)
{
    __shared__ float sv[256];
    __shared__ int   si[256];
    const long row = blockIdx.x;
    const int tid = threadIdx.x;
    float* s = sims + row * 1024L;
    float v0 = s[tid], v1 = s[tid + 256], v2 = s[tid + 512], v3 = s[tid + 768];
    float best = v0; int bi = tid;
    if (v1 > best) { best = v1; bi = tid + 256; }
    if (v2 > best) { best = v2; bi = tid + 512; }
    if (v3 > best) { best = v3; bi = tid + 768; }
    sv[tid] = best; si[tid] = bi; __syncthreads();
    #pragma unroll
    for (int st = 128; st > 0; st >>= 1) {
        if (tid < st) {
            if (sv[tid + st] > sv[tid] ||
                (sv[tid + st] == sv[tid] && si[tid + st] < si[tid])) {
                sv[tid] = sv[tid + st]; si[tid] = si[tid + st];
            }
        }
        __syncthreads();
    }
    const int idx = si[0];
    s[tid]       = (tid       == idx) ? 1.f : 0.f;
    s[tid + 256] = (tid + 256 == idx) ? 1.f : 0.f;
    s[tid + 512] = (tid + 512 == idx) ? 1.f : 0.f;
    s[tid + 768] = (tid + 768 == idx) ? 1.f : 0.f;
    const float* er = emb + (long)idx * 512;
    float* vr = vq_out + row * 512L;
    const float e0 = er[tid], e1 = er[tid + 256];
    vr[tid]       = e0;
    vr[tid + 256] = e1;
    if (OUTH) {
        const bf16 h0 = (bf16)e0, h1 = (bf16)e1;
        vh[row * 512 + tid]       = h0;
        vl[row * 512 + tid]       = (bf16)(e0 - (float)h0);
        vh[row * 512 + tid + 256] = h1;
        vl[row * 512 + tid + 256] = (bf16)(e1 - (float)h1);
    }
}

// ---------------------------------------------------------------- host side
struct EncW {
    const float *wq, *wk, *wv, *wo, *w1, *w2;
    const float *bq, *bk, *bv, *bo, *b1, *b2;
    const float *g1, *be1, *g2, *be2;
};

static void run_encoder_g3(hipStream_t stream, const float* x, const EncW& w,
                           float* qb, bf16* khi, bf16* klo, bf16* vthi, bf16* vtlo,
                           float* ctx, float* Op, float* ml,
                           float* x1, float* hb, float* out)
{
    const int N = 4096, D = 512;
    qkv_gemm<<<dim3(12, 64), 256, 0, stream>>>(
        x, w.wq, w.wk, w.wv, w.bq, w.bk, w.bv, qb, khi, klo, vthi, vtlo);
    flash_attn<4><<<dim3(64, 4, 4), 128, 0, stream>>>(qb, khi, klo, vthi, vtlo, Op, nullptr, ml);
    flash_merge_t<4, false, true><<<256, 256, 0, stream>>>(Op, nullptr, ml, ctx, nullptr, nullptr);
    gemm3<64, false, false, true, false><<<dim3(4, 64), 256, 0, stream>>>(
        ctx, w.wo, w.bo, qb, nullptr, nullptr, D, D, D, D, 1.f);
    add_ln_t<false, true><<<N, 256, 0, stream>>>(x, qb, w.g1, w.be1, x1, nullptr, nullptr);
    gemm3<64, true, false, true, false><<<dim3(4, 64), 256, 0, stream>>>(
        x1, w.w1, w.b1, hb, nullptr, nullptr, D, D, D, D, 1.f);
    gemm3<64, false, false, true, false><<<dim3(4, 64), 256, 0, stream>>>(
        hb, w.w2, w.b2, qb, nullptr, nullptr, D, D, D, D, 1.f);
    add_ln_t<false, true><<<N, 256, 0, stream>>>(x1, qb, w.g2, w.be2, out, nullptr, nullptr);
}

static void run_encoder_g3p(hipStream_t stream, const float* x, const EncW& w,
                            bf16* wsb, int slot0,
                            float* qb, bf16* khi, bf16* klo, bf16* vthi, bf16* vtlo,
                            float* ctx, float* Op, float* ml,
                            float* x1, float* hb, float* out)
{
    const int N = 4096, D = 512;
    auto sh = [&](int i) { return wsb + (long)(slot0 + i) * 524288; };
    auto sl = [&](int i) { return wsb + (long)(slot0 + i) * 524288 + 262144; };
    qkv_gemmp<<<dim3(12, 64), 256, 0, stream>>>(
        x, sh(0), sl(0), sh(1), sl(1), sh(2), sl(2),
        w.bq, w.bk, w.bv, qb, khi, klo, vthi, vtlo);
    flash_attn<4><<<dim3(64, 4, 4), 128, 0, stream>>>(qb, khi, klo, vthi, vtlo, Op, nullptr, ml);
    flash_merge_t<4, false, true><<<256, 256, 0, stream>>>(Op, nullptr, ml, ctx, nullptr, nullptr);
    gemm3p<64, false><<<dim3(4, 64), 256, 0, stream>>>(
        ctx, sh(3), sl(3), w.bo, qb, D, D, D, D);
    add_ln_t<false, true><<<N, 256, 0, stream>>>(x, qb, w.g1, w.be1, x1, nullptr, nullptr);
    gemm3p<64, true><<<dim3(4, 64), 256, 0, stream>>>(
        x1, sh(4), sl(4), w.b1, hb, D, D, D, D);
    gemm3p<64, false><<<dim3(4, 64), 256, 0, stream>>>(
        hb, sh(5), sl(5), w.b2, qb, D, D, D, D);
    add_ln_t<false, true><<<N, 256, 0, stream>>>(x1, qb, w.g2, w.be2, out, nullptr, nullptr);
}

// v15 tier: hilo operands everywhere; 8-way KV split; dead f32 stores gated off
static void run_encoder_g3q(hipStream_t stream,
                            const float* xres,
                            const bf16* xah, const bf16* xal,
                            const EncW& w, bf16* wsb, int slot0,
                            bf16* ctxh, bf16* ctxl, bf16* x1h, bf16* x1l,
                            bf16* hbh, bf16* hbl, bf16* o2h, bf16* o2l,
                            float* qb, bf16* khi, bf16* klo, bf16* vthi, bf16* vtlo,
                            float* ctx, float* OpA, float* OpB, float* ml,
                            float* x1, float* hb, float* out)
{
    const int N = 4096, D = 512;
    auto sh = [&](int i) { return wsb + (long)(slot0 + i) * 524288; };
    auto sl = [&](int i) { return wsb + (long)(slot0 + i) * 524288 + 262144; };
    qkv_gemmq<<<dim3(12, 64), 256, 0, stream>>>(
        xah, xal, sh(0), sl(0), sh(1), sl(1), sh(2), sl(2),
        w.bq, w.bk, w.bv, qb, khi, klo, vthi, vtlo);
    flash_attn<8><<<dim3(64, 4, 8), 128, 0, stream>>>(qb, khi, klo, vthi, vtlo, OpA, OpB, ml);
    flash_merge_t<8, true, false><<<256, 256, 0, stream>>>(OpA, OpB, ml, ctx, ctxh, ctxl);
    gemm3s<false, false, true><<<dim3(8, 128), 128, 0, stream>>>(
        ctxh, ctxl, sh(3), sl(3), w.bo, qb, nullptr, nullptr, D, D, D, D);
    add_ln_t<true, true><<<N, 256, 0, stream>>>(xres, qb, w.g1, w.be1, x1, x1h, x1l);
    gemm3s<true, true, false><<<dim3(8, 128), 128, 0, stream>>>(
        x1h, x1l, sh(4), sl(4), w.b1, hb, hbh, hbl, D, D, D, D);
    gemm3s<false, false, true><<<dim3(8, 128), 128, 0, stream>>>(
        hbh, hbl, sh(5), sl(5), w.b2, qb, nullptr, nullptr, D, D, D, D);
    add_ln_t<true, false><<<N, 256, 0, stream>>>(x1, qb, w.g2, w.be2, out, o2h, o2l);
}

extern "C" void kernel_launch(void* const* d_in, const int* in_sizes, int n_in,
                              void* d_out, int out_size, void* d_ws, size_t ws_size,
                              hipStream_t stream)
{
    const int N = 4096, D = 512, E = 512, F = 4096, KCB = 1024;
    (void)in_sizes; (void)n_in; (void)out_size;

    const float* x_in  = (const float*)d_in[0];
    const float* fc1_w = (const float*)d_in[33];
    const float* fc1_b = (const float*)d_in[34];
    const float* fc2_w = (const float*)d_in[35];
    const float* fc2_b = (const float*)d_in[36];
    const float* emb   = (const float*)d_in[37];

    float* out0 = (float*)d_out;                  // encoded [N,E]
    float* out1 = out0 + (size_t)N * E;           // vq_feat [N,E]
    float* out2 = out1 + (size_t)N * E;           // one_hot [N,K]
    float* out3 = out2 + (size_t)N * KCB;         // decoded [N,F]
    float* out4 = out3 + (size_t)N * F;           // emb copy

    char* arena = (char*)out3;
    const size_t MB = 1024 * 1024;
    float* qb     = (float*)(arena + 0 * MB);
    bf16*  khi    = (bf16*) (arena + 8 * MB);
    bf16*  klo    = (bf16*) (arena + 12 * MB);
    bf16*  vthi   = (bf16*) (arena + 16 * MB);
    bf16*  vtlo   = (bf16*) (arena + 20 * MB);
    float* ctx    = (float*)(arena + 24 * MB);
    float* Op     = (float*)(arena + 32 * MB);    // legacy 4-split partials
    float* decout = (float*)(arena + 56 * MB);
    float* x1     = (float*)(arena + 16 * MB);
    float* hb     = (float*)(arena + 8 * MB);
    float* ml     = (float*)out4;                 // up to 1 MB (2048x128 f32)
    float* embn   = out1;
    float* stage  = (float*)out4;

    EncW ew = { (const float*)d_in[1],  (const float*)d_in[2],  (const float*)d_in[3],
                (const float*)d_in[4],  (const float*)d_in[5],  (const float*)d_in[6],
                (const float*)d_in[7],  (const float*)d_in[8],  (const float*)d_in[9],
                (const float*)d_in[10], (const float*)d_in[11], (const float*)d_in[12],
                (const float*)d_in[13], (const float*)d_in[14], (const float*)d_in[15],
                (const float*)d_in[16] };
    EncW dw = { (const float*)d_in[17], (const float*)d_in[18], (const float*)d_in[19],
                (const float*)d_in[20], (const float*)d_in[21], (const float*)d_in[22],
                (const float*)d_in[23], (const float*)d_in[24], (const float*)d_in[25],
                (const float*)d_in[26], (const float*)d_in[27], (const float*)d_in[28],
                (const float*)d_in[29], (const float*)d_in[30], (const float*)d_in[31],
                (const float*)d_in[32] };

    const size_t WS_NEED1 = 24117248;    // v10 tier: weights + emb hilo
    const size_t WS_NEED2 = 74448896;    // v11+ tier: + 6 activation hilo slots
    const bool pre2 = (d_ws != nullptr) && (ws_size >= WS_NEED2);
    const bool pre1 = !pre2 && (d_ws != nullptr) && (ws_size >= WS_NEED1);

    if (pre2 || pre1) {
        bf16* wsb = (bf16*)d_ws;
        bf16* f2h = wsb + 6815744;  bf16* f2l = f2h + 2097152;
        bf16* enh = wsb + 11010048; bf16* enl = enh + 524288;

        W14 ptrs;
        ptrs.w[0]  = ew.wq; ptrs.w[1]  = ew.wk; ptrs.w[2]  = ew.wv;
        ptrs.w[3]  = ew.wo; ptrs.w[4]  = ew.w1; ptrs.w[5]  = ew.w2;
        ptrs.w[6]  = dw.wq; ptrs.w[7]  = dw.wk; ptrs.w[8]  = dw.wv;
        ptrs.w[9]  = dw.wo; ptrs.w[10] = dw.w1; ptrs.w[11] = dw.w2;
        ptrs.w[12] = fc1_w; ptrs.w[13] = fc2_w;
        convert_weights<<<dim3(16, 16, 21), 256, 0, stream>>>(ptrs, wsb);
        normalize_emb_p<<<KCB, 256, 0, stream>>>(emb, enh, enl);

        if (pre2) {
            auto AH = [&](int s_) { return wsb + 12058624L + (long)s_ * 4194304; };
            auto AL = [&](int s_) { return wsb + 12058624L + (long)s_ * 4194304 + 2097152; };
            bf16 *xah = AH(0), *xal = AL(0);
            bf16 *cth = AH(1), *ctl = AL(1);
            bf16 *x1h = AH(2), *x1l = AL(2);
            bf16 *hbh = AH(3), *hbl = AL(3);
            bf16 *o2h = AH(4), *o2l = AL(4);
            bf16 *f1h = AH(5), *f1l = AL(5);

            // 8-split Op partials: s<4 -> arena [24,56) (ctx f32 dead in this
            // tier); s>=4 -> ws activation slots 2-5 (dead during flash+merge,
            // first rewritten by LN1 which runs after merge).
            float* OpA = (float*)(arena + 24 * MB);            // 32 MB
            float* OpB = (float*)AH(2);                        // 32 MB (slots 2-5)

            convert_x<<<1024, 256, 0, stream>>>(x_in, xah, xal);

            // ---- phase E
            run_encoder_g3q(stream, x_in, xah, xal, ew, wsb, 0,
                            cth, ctl, x1h, x1l, hbh, hbl, o2h, o2l,
                            qb, khi, klo, vthi, vtlo, ctx, OpA, OpB, ml, x1, hb, ctx);
            // ---- phase F: fc1 (A = o2h/o2l); out0 f32 is the encoded output
            gemm3s<false, true, true><<<dim3(8, 128), 128, 0, stream>>>(
                o2h, o2l, wsb + 12L * 524288, wsb + 12L * 524288 + 262144,
                fc1_b, out0, f1h, f1l, D, D, D, E);
            // ---- phase V: sims (out2 f32 read by vq_select)
            gemm3s<false, false, true><<<dim3(16, 128), 128, 0, stream>>>(
                f1h, f1l, enh, enl, nullptr, out2, nullptr, nullptr, E, E, E, KCB);
            vq_select_t<true><<<N, 256, 0, stream>>>(out2, emb, out1, xah, xal);
            // ---- phase D
            run_encoder_g3q(stream, out1, xah, xal, dw, wsb, 6,
                            cth, ctl, x1h, x1l, hbh, hbl, o2h, o2l,
                            qb, khi, klo, vthi, vtlo, ctx, OpA, OpB, ml, x1, hb, decout);
            // ---- phase G: fc2 single dispatch
            gemm3q<128, true, false><<<dim3(F / 128, N / 128), 256, 0, stream>>>(
                o2h, o2l, f2h, f2l, fc2_b, out3, nullptr, nullptr, D, D, D, F);

            (void)hipMemcpyAsync(out4, emb, (size_t)KCB * E * sizeof(float), hipMemcpyDeviceToDevice, stream);
        } else {
            // ---- v10 tier (4-split flash, unchanged)
            run_encoder_g3p(stream, x_in, ew, wsb, 0, qb, khi, klo, vthi, vtlo, ctx, Op, ml, x1, hb, ctx);
            gemm3p<64, false><<<dim3(4, 64), 256, 0, stream>>>(
                ctx, wsb + 12L * 524288, wsb + 12L * 524288 + 262144, fc1_b, out0, D, D, D, E);
            gemm3p<128, false><<<dim3(8, 32), 256, 0, stream>>>(
                out0, enh, enl, nullptr, out2, E, E, E, KCB);
            vq_select_t<false><<<N, 256, 0, stream>>>(out2, emb, out1, nullptr, nullptr);
            run_encoder_g3p(stream, out1, dw, wsb, 6, qb, khi, klo, vthi, vtlo, ctx, Op, ml, x1, hb, decout);
            (void)hipMemcpyAsync(stage, decout + (size_t)3584 * D, (size_t)512 * D * sizeof(float),
                                 hipMemcpyDeviceToDevice, stream);
            gemm3p<128, true><<<dim3(F / 128, 3584 / 128), 256, 0, stream>>>(
                decout, f2h, f2l, fc2_b, out3, D, D, D, F);
            gemm3p<128, true><<<dim3(F / 128, 512 / 128), 256, 0, stream>>>(
                stage, f2h, f2l, fc2_b, out3 + (size_t)3584 * F, D, D, D, F);
            (void)hipMemcpyAsync(out4, emb, (size_t)KCB * E * sizeof(float), hipMemcpyDeviceToDevice, stream);
        }
    } else {
        // ---- legacy fallback (4-split flash, unchanged)
        normalize_emb<<<KCB, 256, 0, stream>>>(emb, embn);
        run_encoder_g3(stream, x_in, ew, qb, khi, klo, vthi, vtlo, ctx, Op, ml, x1, hb, ctx);
        gemm3<64, false, false, true, false><<<dim3(4, 64), 256, 0, stream>>>(
            ctx, fc1_w, fc1_b, out0, nullptr, nullptr, D, D, E, E, 1.f);
        gemm3<128, false, false, false, false><<<dim3(8, 32), 256, 0, stream>>>(
            out0, embn, nullptr, out2, nullptr, nullptr, E, E, E, KCB, 1.f);
        vq_select_t<false><<<N, 256, 0, stream>>>(out2, emb, out1, nullptr, nullptr);
        run_encoder_g3(stream, out1, dw, qb, khi, klo, vthi, vtlo, ctx, Op, ml, x1, hb, decout);
        (void)hipMemcpyAsync(stage, decout + (size_t)3584 * D, (size_t)512 * D * sizeof(float),
                             hipMemcpyDeviceToDevice, stream);
        gemm3<128, true, false, true, false><<<dim3(F / 128, 3584 / 128), 256, 0, stream>>>(
            decout, fc2_w, fc2_b, out3, nullptr, nullptr, D, D, F, F, 1.f);
        gemm3<128, true, false, true, false><<<dim3(F / 128, 512 / 128), 256, 0, stream>>>(
            stage, fc2_w, fc2_b, out3 + (size_t)3584 * F, nullptr, nullptr, D, D, F, F, 1.f);
        (void)hipMemcpyAsync(out4, emb, (size_t)KCB * E * sizeof(float), hipMemcpyDeviceToDevice, stream);
    }
}

// Round 13
// 800.515 us; speedup vs baseline: 1.0400x; 1.0400x over previous
//
#include <hip/hip_runtime.h>
#include <hip/hip_bf16.h>
#include <stdint.h>

typedef __bf16 bf16;
typedef __bf16 bf16x8 __attribute__((ext_vector_type(8)));
typedef float  f32x4v __attribute__((ext_vector_type(4)));

__device__ __forceinline__ void cvt8(const float* v, bf16x8& hh, bf16x8& ll) {
    #pragma unroll
    for (int j = 0; j < 8; j++) {
        bf16 b = (bf16)v[j]; hh[j] = b; ll[j] = (bf16)(v[j] - (float)b);
    }
}

// ---------------------------------------------------------------- reductions
__device__ __forceinline__ float block_reduce_sum256(float v) {
    __shared__ float red[256];
    int tid = threadIdx.x;
    red[tid] = v; __syncthreads();
    #pragma unroll
    for (int s = 128; s > 0; s >>= 1) {
        if (tid < s) red[tid] += red[tid + s];
        __syncthreads();
    }
    float r = red[0]; __syncthreads();
    return r;
}

// ---------------------------------------------------------------- bf16x3 split-MFMA GEMM (legacy: f32 A+B, in-kernel convert)
template<int BMT, bool RELU, bool TRANS, bool BNAT, bool HILO>
__global__ __launch_bounds__(256, 2)
void gemm3(const float* __restrict__ A, const float* __restrict__ B,
           const float* __restrict__ bias, float* __restrict__ C,
           bf16* __restrict__ Chi, bf16* __restrict__ Clo,
           int K, int lda, int ldb, int ldc, float alpha)
{
    constexpr int BN = 128, TK = 32;
    constexpr int RM = BMT / 32;
    __shared__ __align__(16) bf16 Ah[BMT * TK];
    __shared__ __align__(16) bf16 Al[BMT * TK];
    __shared__ __align__(16) bf16 Bh[BN * TK];
    __shared__ __align__(16) bf16 Bl[BN * TK];

    const int tid  = threadIdx.x;
    const int wave = tid >> 6, lane = tid & 63;
    const int wr = wave >> 1, wc = wave & 1;
    const long bm = (long)blockIdx.y * BMT;
    const long bn = (long)blockIdx.x * BN;
    const int fr = lane & 15, fq = lane >> 4;

    f32x4v acc[RM][4] = {};

    for (int k0 = 0; k0 < K; k0 += TK) {
        #pragma unroll
        for (int it = 0; it < BMT / 64; it++) {
            const int c = it * 256 + tid;
            const int r = c >> 2, k8 = c & 3;
            const float* src = A + (bm + r) * (long)lda + k0 + k8 * 8;
            float4 f0 = ((const float4*)src)[0], f1 = ((const float4*)src)[1];
            float v[8] = {f0.x, f0.y, f0.z, f0.w, f1.x, f1.y, f1.z, f1.w};
            bf16x8 hh, ll; cvt8(v, hh, ll);
            *(bf16x8*)&Ah[r * TK + k8 * 8] = hh;
            *(bf16x8*)&Al[r * TK + k8 * 8] = ll;
        }
        if (BNAT) {
            const int col = tid & 127, bkh = (tid >> 7) * 16;
            const float* src = B + (long)(k0 + bkh) * ldb + bn + col;
            float v[16];
            #pragma unroll
            for (int kk = 0; kk < 16; kk++) v[kk] = src[(long)kk * ldb];
            bf16x8 h0, l0, h1, l1; cvt8(v, h0, l0); cvt8(v + 8, h1, l1);
            bf16* hd = &Bh[col * TK + bkh];
            bf16* ld_ = &Bl[col * TK + bkh];
            ((bf16x8*)hd)[0] = h0; ((bf16x8*)hd)[1] = h1;
            ((bf16x8*)ld_)[0] = l0; ((bf16x8*)ld_)[1] = l1;
        } else {
            #pragma unroll
            for (int it = 0; it < 2; it++) {
                const int c = it * 256 + tid;
                const int r = c >> 2, k8 = c & 3;
                const float* src = B + (bn + r) * (long)ldb + k0 + k8 * 8;
                float4 f0 = ((const float4*)src)[0], f1 = ((const float4*)src)[1];
                float v[8] = {f0.x, f0.y, f0.z, f0.w, f1.x, f1.y, f1.z, f1.w};
                bf16x8 hh, ll; cvt8(v, hh, ll);
                *(bf16x8*)&Bh[r * TK + k8 * 8] = hh;
                *(bf16x8*)&Bl[r * TK + k8 * 8] = ll;
            }
        }
        __syncthreads();

        bf16x8 ah[RM], am[RM], bh[4], bm_[4];
        #pragma unroll
        for (int i = 0; i < RM; i++) {
            const int r = (wr * (BMT / 2) + i * 16 + fr) * TK + fq * 8;
            ah[i] = *(const bf16x8*)&Ah[r];
            am[i] = *(const bf16x8*)&Al[r];
        }
        #pragma unroll
        for (int j = 0; j < 4; j++) {
            const int r = (wc * 64 + j * 16 + fr) * TK + fq * 8;
            bh[j] = *(const bf16x8*)&Bh[r];
            bm_[j] = *(const bf16x8*)&Bl[r];
        }
        #pragma unroll
        for (int i = 0; i < RM; i++)
            #pragma unroll
            for (int j = 0; j < 4; j++) {
                acc[i][j] = __builtin_amdgcn_mfma_f32_16x16x32_bf16(am[i], bh[j], acc[i][j], 0, 0, 0);
                acc[i][j] = __builtin_amdgcn_mfma_f32_16x16x32_bf16(ah[i], bm_[j], acc[i][j], 0, 0, 0);
                acc[i][j] = __builtin_amdgcn_mfma_f32_16x16x32_bf16(ah[i], bh[j], acc[i][j], 0, 0, 0);
            }
        __syncthreads();
    }

    #pragma unroll
    for (int i = 0; i < RM; i++) {
        #pragma unroll
        for (int j = 0; j < 4; j++) {
            const long col = bn + wc * 64 + j * 16 + fr;
            const float bv = bias ? bias[col] : 0.f;
            #pragma unroll
            for (int r = 0; r < 4; r++) {
                const long row = bm + wr * (BMT / 2) + i * 16 + fq * 4 + r;
                float v = acc[i][j][r] * alpha + bv;
                if (RELU) v = fmaxf(v, 0.f);
                const long idx = TRANS ? (col * (long)ldc + row) : (row * (long)ldc + col);
                if (HILO) {
                    bf16 hh = (bf16)v;
                    Chi[idx] = hh;
                    Clo[idx] = (bf16)(v - (float)hh);
                } else {
                    C[idx] = v;
                }
            }
        }
    }
}

// ---------------------------------------------------------------- bf16x3 GEMM, pre-converted B (f32 A) -- v10 tier
template<int BMT, bool RELU>
__global__ __launch_bounds__(256, 2)
void gemm3p(const float* __restrict__ A,
            const bf16* __restrict__ Bph, const bf16* __restrict__ Bpl,
            const float* __restrict__ bias, float* __restrict__ C,
            int K, int lda, int ldb, int ldc)
{
    constexpr int BN = 128, TK = 32;
    constexpr int RM = BMT / 32;
    __shared__ __align__(16) bf16 Ah[BMT * TK];
    __shared__ __align__(16) bf16 Al[BMT * TK];
    __shared__ __align__(16) bf16 Bh[BN * TK];
    __shared__ __align__(16) bf16 Bl[BN * TK];

    const int tid  = threadIdx.x;
    const int wave = tid >> 6, lane = tid & 63;
    const int wr = wave >> 1, wc = wave & 1;
    const long bm = (long)blockIdx.y * BMT;
    const long bn = (long)blockIdx.x * BN;
    const int fr = lane & 15, fq = lane >> 4;

    f32x4v acc[RM][4] = {};

    for (int k0 = 0; k0 < K; k0 += TK) {
        #pragma unroll
        for (int it = 0; it < BMT / 64; it++) {
            const int c = it * 256 + tid;
            const int r = c >> 2, k8 = c & 3;
            const float* src = A + (bm + r) * (long)lda + k0 + k8 * 8;
            float4 f0 = ((const float4*)src)[0], f1 = ((const float4*)src)[1];
            float v[8] = {f0.x, f0.y, f0.z, f0.w, f1.x, f1.y, f1.z, f1.w};
            bf16x8 hh, ll; cvt8(v, hh, ll);
            *(bf16x8*)&Ah[r * TK + k8 * 8] = hh;
            *(bf16x8*)&Al[r * TK + k8 * 8] = ll;
        }
        #pragma unroll
        for (int it = 0; it < 2; it++) {
            const int c = it * 256 + tid;
            const int r = c >> 2, k8 = c & 3;
            const long bo = (bn + r) * (long)ldb + k0 + k8 * 8;
            *(uint4*)&Bh[r * TK + k8 * 8] = *(const uint4*)&Bph[bo];
            *(uint4*)&Bl[r * TK + k8 * 8] = *(const uint4*)&Bpl[bo];
        }
        __syncthreads();

        bf16x8 ah[RM], am[RM], bh[4], bm_[4];
        #pragma unroll
        for (int i = 0; i < RM; i++) {
            const int r = (wr * (BMT / 2) + i * 16 + fr) * TK + fq * 8;
            ah[i] = *(const bf16x8*)&Ah[r];
            am[i] = *(const bf16x8*)&Al[r];
        }
        #pragma unroll
        for (int j = 0; j < 4; j++) {
            const int r = (wc * 64 + j * 16 + fr) * TK + fq * 8;
            bh[j] = *(const bf16x8*)&Bh[r];
            bm_[j] = *(const bf16x8*)&Bl[r];
        }
        #pragma unroll
        for (int i = 0; i < RM; i++)
            #pragma unroll
            for (int j = 0; j < 4; j++) {
                acc[i][j] = __builtin_amdgcn_mfma_f32_16x16x32_bf16(am[i], bh[j], acc[i][j], 0, 0, 0);
                acc[i][j] = __builtin_amdgcn_mfma_f32_16x16x32_bf16(ah[i], bm_[j], acc[i][j], 0, 0, 0);
                acc[i][j] = __builtin_amdgcn_mfma_f32_16x16x32_bf16(ah[i], bh[j], acc[i][j], 0, 0, 0);
            }
        __syncthreads();
    }

    #pragma unroll
    for (int i = 0; i < RM; i++) {
        #pragma unroll
        for (int j = 0; j < 4; j++) {
            const long col = bn + wc * 64 + j * 16 + fr;
            const float bv = bias ? bias[col] : 0.f;
            #pragma unroll
            for (int r = 0; r < 4; r++) {
                const long row = bm + wr * (BMT / 2) + i * 16 + fq * 4 + r;
                float v = acc[i][j][r] + bv;
                if (RELU) v = fmaxf(v, 0.f);
                C[row * (long)ldc + col] = v;
            }
        }
    }
}

// ---------------------------------------------------------------- bf16x3 GEMM, pre-converted A AND B (hi/lo), optional hilo out
template<int BMT, bool RELU, bool OUTH>
__global__ __launch_bounds__(256, 2)
void gemm3q(const bf16* __restrict__ Agh, const bf16* __restrict__ Agl,
            const bf16* __restrict__ Bph, const bf16* __restrict__ Bpl,
            const float* __restrict__ bias, float* __restrict__ C,
            bf16* __restrict__ Oh, bf16* __restrict__ Ol,
            int K, int lda, int ldb, int ldc)
{
    constexpr int BN = 128, TK = 32;
    constexpr int RM = BMT / 32;
    __shared__ __align__(16) bf16 Ah[BMT * TK];
    __shared__ __align__(16) bf16 Al[BMT * TK];
    __shared__ __align__(16) bf16 Bh[BN * TK];
    __shared__ __align__(16) bf16 Bl[BN * TK];

    const int tid  = threadIdx.x;
    const int wave = tid >> 6, lane = tid & 63;
    const int wr = wave >> 1, wc = wave & 1;
    const long bm = (long)blockIdx.y * BMT;
    const long bn = (long)blockIdx.x * BN;
    const int fr = lane & 15, fq = lane >> 4;

    f32x4v acc[RM][4] = {};

    for (int k0 = 0; k0 < K; k0 += TK) {
        #pragma unroll
        for (int it = 0; it < (BMT + 63) / 64; it++) {
            const int c = it * 256 + tid;
            const int r = c >> 2, k8 = c & 3;
            const long ao = (bm + r) * (long)lda + k0 + k8 * 8;
            *(uint4*)&Ah[r * TK + k8 * 8] = *(const uint4*)&Agh[ao];
            *(uint4*)&Al[r * TK + k8 * 8] = *(const uint4*)&Agl[ao];
        }
        #pragma unroll
        for (int it = 0; it < 2; it++) {
            const int c = it * 256 + tid;
            const int r = c >> 2, k8 = c & 3;
            const long bo = (bn + r) * (long)ldb + k0 + k8 * 8;
            *(uint4*)&Bh[r * TK + k8 * 8] = *(const uint4*)&Bph[bo];
            *(uint4*)&Bl[r * TK + k8 * 8] = *(const uint4*)&Bpl[bo];
        }
        __syncthreads();

        bf16x8 ah[RM], am[RM], bh[4], bm_[4];
        #pragma unroll
        for (int i = 0; i < RM; i++) {
            const int r = (wr * (BMT / 2) + i * 16 + fr) * TK + fq * 8;
            ah[i] = *(const bf16x8*)&Ah[r];
            am[i] = *(const bf16x8*)&Al[r];
        }
        #pragma unroll
        for (int j = 0; j < 4; j++) {
            const int r = (wc * 64 + j * 16 + fr) * TK + fq * 8;
            bh[j] = *(const bf16x8*)&Bh[r];
            bm_[j] = *(const bf16x8*)&Bl[r];
        }
        #pragma unroll
        for (int i = 0; i < RM; i++)
            #pragma unroll
            for (int j = 0; j < 4; j++) {
                acc[i][j] = __builtin_amdgcn_mfma_f32_16x16x32_bf16(am[i], bh[j], acc[i][j], 0, 0, 0);
                acc[i][j] = __builtin_amdgcn_mfma_f32_16x16x32_bf16(ah[i], bm_[j], acc[i][j], 0, 0, 0);
                acc[i][j] = __builtin_amdgcn_mfma_f32_16x16x32_bf16(ah[i], bh[j], acc[i][j], 0, 0, 0);
            }
        __syncthreads();
    }

    #pragma unroll
    for (int i = 0; i < RM; i++) {
        #pragma unroll
        for (int j = 0; j < 4; j++) {
            const long col = bn + wc * 64 + j * 16 + fr;
            const float bv = bias ? bias[col] : 0.f;
            #pragma unroll
            for (int r = 0; r < 4; r++) {
                const long row = bm + wr * (BMT / 2) + i * 16 + fq * 4 + r;
                float v = acc[i][j][r] + bv;
                if (RELU) v = fmaxf(v, 0.f);
                const long idx = row * (long)ldc + col;
                C[idx] = v;
                if (OUTH) {
                    const bf16 hh = (bf16)v;
                    Oh[idx] = hh;
                    Ol[idx] = (bf16)(v - (float)hh);
                }
            }
        }
    }
}

// ---------------------------------------------------------------- fused QKV projection (legacy f32 A+W)
__global__ __launch_bounds__(256, 2)
void qkv_gemm(const float* __restrict__ X,
              const float* __restrict__ Wq, const float* __restrict__ Wk, const float* __restrict__ Wv,
              const float* __restrict__ Bq, const float* __restrict__ Bk, const float* __restrict__ Bv,
              float* __restrict__ Qo, bf16* __restrict__ Khi, bf16* __restrict__ Klo,
              bf16* __restrict__ Vthi, bf16* __restrict__ Vtlo)
{
    constexpr int TK = 32, D = 512, N = 4096;
    __shared__ __align__(16) bf16 Ah[64 * TK];
    __shared__ __align__(16) bf16 Al[64 * TK];
    __shared__ __align__(16) bf16 Bh[128 * TK];
    __shared__ __align__(16) bf16 Bl[128 * TK];

    const int tid  = threadIdx.x;
    const int wave = tid >> 6, lane = tid & 63;
    const int wr = wave >> 1, wc = wave & 1;
    const int sel = blockIdx.x >> 2, wcol0 = (blockIdx.x & 3) * 128;
    const long bm = (long)blockIdx.y * 64;
    const int fr = lane & 15, fq = lane >> 4;

    const float* W  = sel == 0 ? Wq : (sel == 1 ? Wk : Wv);
    const float* Bb = sel == 0 ? Bq : (sel == 1 ? Bk : Bv);

    f32x4v acc[2][4] = {};

    for (int k0 = 0; k0 < D; k0 += TK) {
        {
            const int r = tid >> 2, k8 = tid & 3;
            const float* src = X + (bm + r) * (long)D + k0 + k8 * 8;
            float4 f0 = ((const float4*)src)[0], f1 = ((const float4*)src)[1];
            float v[8] = {f0.x, f0.y, f0.z, f0.w, f1.x, f1.y, f1.z, f1.w};
            bf16x8 hh, ll; cvt8(v, hh, ll);
            *(bf16x8*)&Ah[r * TK + k8 * 8] = hh;
            *(bf16x8*)&Al[r * TK + k8 * 8] = ll;
        }
        {
            const int col = tid & 127, bkh = (tid >> 7) * 16;
            const float* src = W + (long)(k0 + bkh) * D + wcol0 + col;
            float v[16];
            #pragma unroll
            for (int kk = 0; kk < 16; kk++) v[kk] = src[(long)kk * D];
            bf16x8 h0, l0, h1, l1; cvt8(v, h0, l0); cvt8(v + 8, h1, l1);
            bf16* hd = &Bh[col * TK + bkh];
            bf16* ld_ = &Bl[col * TK + bkh];
            ((bf16x8*)hd)[0] = h0; ((bf16x8*)hd)[1] = h1;
            ((bf16x8*)ld_)[0] = l0; ((bf16x8*)ld_)[1] = l1;
        }
        __syncthreads();

        bf16x8 ah[2], am[2], bh[4], bm_[4];
        #pragma unroll
        for (int i = 0; i < 2; i++) {
            const int r = (wr * 32 + i * 16 + fr) * TK + fq * 8;
            ah[i] = *(const bf16x8*)&Ah[r];
            am[i] = *(const bf16x8*)&Al[r];
        }
        #pragma unroll
        for (int j = 0; j < 4; j++) {
            const int r = (wc * 64 + j * 16 + fr) * TK + fq * 8;
            bh[j] = *(const bf16x8*)&Bh[r];
            bm_[j] = *(const bf16x8*)&Bl[r];
        }
        #pragma unroll
        for (int i = 0; i < 2; i++)
            #pragma unroll
            for (int j = 0; j < 4; j++) {
                acc[i][j] = __builtin_amdgcn_mfma_f32_16x16x32_bf16(am[i], bh[j], acc[i][j], 0, 0, 0);
                acc[i][j] = __builtin_amdgcn_mfma_f32_16x16x32_bf16(ah[i], bm_[j], acc[i][j], 0, 0, 0);
                acc[i][j] = __builtin_amdgcn_mfma_f32_16x16x32_bf16(ah[i], bh[j], acc[i][j], 0, 0, 0);
            }
        __syncthreads();
    }

    #pragma unroll
    for (int i = 0; i < 2; i++) {
        #pragma unroll
        for (int j = 0; j < 4; j++) {
            const int col = wc * 64 + j * 16 + fr;
            const float bv = Bb[wcol0 + col];
            #pragma unroll
            for (int r = 0; r < 4; r++) {
                const long row = bm + wr * 32 + i * 16 + fq * 4 + r;
                const float v = acc[i][j][r] + bv;
                if (sel == 0) {
                    Qo[row * D + wcol0 + col] = v;
                } else {
                    const bf16 hh = (bf16)v;
                    const bf16 ll = (bf16)(v - (float)hh);
                    const long idx = (sel == 1) ? (row * (long)D + wcol0 + col)
                                                : ((long)(wcol0 + col) * N + row);
                    if (sel == 1) { Khi[idx] = hh; Klo[idx] = ll; }
                    else          { Vthi[idx] = hh; Vtlo[idx] = ll; }
                }
            }
        }
    }
}

// ---------------------------------------------------------------- fused QKV, pre-converted W^T, f32 X (v10 tier)
__global__ __launch_bounds__(256, 2)
void qkv_gemmp(const float* __restrict__ X,
               const bf16* __restrict__ Wqh, const bf16* __restrict__ Wql,
               const bf16* __restrict__ Wkh, const bf16* __restrict__ Wkl,
               const bf16* __restrict__ Wvh, const bf16* __restrict__ Wvl,
               const float* __restrict__ Bq, const float* __restrict__ Bk, const float* __restrict__ Bv,
               float* __restrict__ Qo, bf16* __restrict__ Khi, bf16* __restrict__ Klo,
               bf16* __restrict__ Vthi, bf16* __restrict__ Vtlo)
{
    constexpr int TK = 32, D = 512, N = 4096;
    __shared__ __align__(16) bf16 Ah[64 * TK];
    __shared__ __align__(16) bf16 Al[64 * TK];
    __shared__ __align__(16) bf16 Bh[128 * TK];
    __shared__ __align__(16) bf16 Bl[128 * TK];

    const int tid  = threadIdx.x;
    const int wave = tid >> 6, lane = tid & 63;
    const int wr = wave >> 1, wc = wave & 1;
    const int sel = blockIdx.x >> 2, wcol0 = (blockIdx.x & 3) * 128;
    const long bm = (long)blockIdx.y * 64;
    const int fr = lane & 15, fq = lane >> 4;

    const bf16* Wh = sel == 0 ? Wqh : (sel == 1 ? Wkh : Wvh);
    const bf16* Wl = sel == 0 ? Wql : (sel == 1 ? Wkl : Wvl);
    const float* Bb = sel == 0 ? Bq : (sel == 1 ? Bk : Bv);

    f32x4v acc[2][4] = {};

    for (int k0 = 0; k0 < D; k0 += TK) {
        {
            const int r = tid >> 2, k8 = tid & 3;
            const float* src = X + (bm + r) * (long)D + k0 + k8 * 8;
            float4 f0 = ((const float4*)src)[0], f1 = ((const float4*)src)[1];
            float v[8] = {f0.x, f0.y, f0.z, f0.w, f1.x, f1.y, f1.z, f1.w};
            bf16x8 hh, ll; cvt8(v, hh, ll);
            *(bf16x8*)&Ah[r * TK + k8 * 8] = hh;
            *(bf16x8*)&Al[r * TK + k8 * 8] = ll;
        }
        #pragma unroll
        for (int it = 0; it < 2; it++) {
            const int c = it * 256 + tid;
            const int r = c >> 2, k8 = c & 3;
            const long bo = (long)(wcol0 + r) * D + k0 + k8 * 8;
            *(uint4*)&Bh[r * TK + k8 * 8] = *(const uint4*)&Wh[bo];
            *(uint4*)&Bl[r * TK + k8 * 8] = *(const uint4*)&Wl[bo];
        }
        __syncthreads();

        bf16x8 ah[2], am[2], bh[4], bm_[4];
        #pragma unroll
        for (int i = 0; i < 2; i++) {
            const int r = (wr * 32 + i * 16 + fr) * TK + fq * 8;
            ah[i] = *(const bf16x8*)&Ah[r];
            am[i] = *(const bf16x8*)&Al[r];
        }
        #pragma unroll
        for (int j = 0; j < 4; j++) {
            const int r = (wc * 64 + j * 16 + fr) * TK + fq * 8;
            bh[j] = *(const bf16x8*)&Bh[r];
            bm_[j] = *(const bf16x8*)&Bl[r];
        }
        #pragma unroll
        for (int i = 0; i < 2; i++)
            #pragma unroll
            for (int j = 0; j < 4; j++) {
                acc[i][j] = __builtin_amdgcn_mfma_f32_16x16x32_bf16(am[i], bh[j], acc[i][j], 0, 0, 0);
                acc[i][j] = __builtin_amdgcn_mfma_f32_16x16x32_bf16(ah[i], bm_[j], acc[i][j], 0, 0, 0);
                acc[i][j] = __builtin_amdgcn_mfma_f32_16x16x32_bf16(ah[i], bh[j], acc[i][j], 0, 0, 0);
            }
        __syncthreads();
    }

    #pragma unroll
    for (int i = 0; i < 2; i++) {
        #pragma unroll
        for (int j = 0; j < 4; j++) {
            const int col = wc * 64 + j * 16 + fr;
            const float bv = Bb[wcol0 + col];
            #pragma unroll
            for (int r = 0; r < 4; r++) {
                const long row = bm + wr * 32 + i * 16 + fq * 4 + r;
                const float v = acc[i][j][r] + bv;
                if (sel == 0) {
                    Qo[row * D + wcol0 + col] = v;
                } else {
                    const bf16 hh = (bf16)v;
                    const bf16 ll = (bf16)(v - (float)hh);
                    const long idx = (sel == 1) ? (row * (long)D + wcol0 + col)
                                                : ((long)(wcol0 + col) * N + row);
                    if (sel == 1) { Khi[idx] = hh; Klo[idx] = ll; }
                    else          { Vthi[idx] = hh; Vtlo[idx] = ll; }
                }
            }
        }
    }
}

// ---------------------------------------------------------------- fused QKV, pre-converted W^T AND hilo X (v11 tier)
__global__ __launch_bounds__(256, 2)
void qkv_gemmq(const bf16* __restrict__ Xh, const bf16* __restrict__ Xl,
               const bf16* __restrict__ Wqh, const bf16* __restrict__ Wql,
               const bf16* __restrict__ Wkh, const bf16* __restrict__ Wkl,
               const bf16* __restrict__ Wvh, const bf16* __restrict__ Wvl,
               const float* __restrict__ Bq, const float* __restrict__ Bk, const float* __restrict__ Bv,
               float* __restrict__ Qo, bf16* __restrict__ Khi, bf16* __restrict__ Klo,
               bf16* __restrict__ Vthi, bf16* __restrict__ Vtlo)
{
    constexpr int TK = 32, D = 512, N = 4096;
    __shared__ __align__(16) bf16 Ah[64 * TK];
    __shared__ __align__(16) bf16 Al[64 * TK];
    __shared__ __align__(16) bf16 Bh[128 * TK];
    __shared__ __align__(16) bf16 Bl[128 * TK];

    const int tid  = threadIdx.x;
    const int wave = tid >> 6, lane = tid & 63;
    const int wr = wave >> 1, wc = wave & 1;
    const int sel = blockIdx.x >> 2, wcol0 = (blockIdx.x & 3) * 128;
    const long bm = (long)blockIdx.y * 64;
    const int fr = lane & 15, fq = lane >> 4;

    const bf16* Wh = sel == 0 ? Wqh : (sel == 1 ? Wkh : Wvh);
    const bf16* Wl = sel == 0 ? Wql : (sel == 1 ? Wkl : Wvl);
    const float* Bb = sel == 0 ? Bq : (sel == 1 ? Bk : Bv);

    f32x4v acc[2][4] = {};

    for (int k0 = 0; k0 < D; k0 += TK) {
        {
            const int r = tid >> 2, k8 = tid & 3;
            const long ao = (bm + r) * (long)D + k0 + k8 * 8;
            *(uint4*)&Ah[r * TK + k8 * 8] = *(const uint4*)&Xh[ao];
            *(uint4*)&Al[r * TK + k8 * 8] = *(const uint4*)&Xl[ao];
        }
        #pragma unroll
        for (int it = 0; it < 2; it++) {
            const int c = it * 256 + tid;
            const int r = c >> 2, k8 = c & 3;
            const long bo = (long)(wcol0 + r) * D + k0 + k8 * 8;
            *(uint4*)&Bh[r * TK + k8 * 8] = *(const uint4*)&Wh[bo];
            *(uint4*)&Bl[r * TK + k8 * 8] = *(const uint4*)&Wl[bo];
        }
        __syncthreads();

        bf16x8 ah[2], am[2], bh[4], bm_[4];
        #pragma unroll
        for (int i = 0; i < 2; i++) {
            const int r = (wr * 32 + i * 16 + fr) * TK + fq * 8;
            ah[i] = *(const bf16x8*)&Ah[r];
            am[i] = *(const bf16x8*)&Al[r];
        }
        #pragma unroll
        for (int j = 0; j < 4; j++) {
            const int r = (wc * 64 + j * 16 + fr) * TK + fq * 8;
            bh[j] = *(const bf16x8*)&Bh[r];
            bm_[j] = *(const bf16x8*)&Bl[r];
        }
        #pragma unroll
        for (int i = 0; i < 2; i++)
            #pragma unroll
            for (int j = 0; j < 4; j++) {
                acc[i][j] = __builtin_amdgcn_mfma_f32_16x16x32_bf16(am[i], bh[j], acc[i][j], 0, 0, 0);
                acc[i][j] = __builtin_amdgcn_mfma_f32_16x16x32_bf16(ah[i], bm_[j], acc[i][j], 0, 0, 0);
                acc[i][j] = __builtin_amdgcn_mfma_f32_16x16x32_bf16(ah[i], bh[j], acc[i][j], 0, 0, 0);
            }
        __syncthreads();
    }

    #pragma unroll
    for (int i = 0; i < 2; i++) {
        #pragma unroll
        for (int j = 0; j < 4; j++) {
            const int col = wc * 64 + j * 16 + fr;
            const float bv = Bb[wcol0 + col];
            #pragma unroll
            for (int r = 0; r < 4; r++) {
                const long row = bm + wr * 32 + i * 16 + fq * 4 + r;
                const float v = acc[i][j][r] + bv;
                if (sel == 0) {
                    Qo[row * D + wcol0 + col] = v;
                } else {
                    const bf16 hh = (bf16)v;
                    const bf16 ll = (bf16)(v - (float)hh);
                    const long idx = (sel == 1) ? (row * (long)D + wcol0 + col)
                                                : ((long)(wcol0 + col) * N + row);
                    if (sel == 1) { Khi[idx] = hh; Klo[idx] = ll; }
                    else          { Vthi[idx] = hh; Vtlo[idx] = ll; }
                }
            }
        }
    }
}

// ---------------------------------------------------------------- weight pre-convert + transpose
struct W14 { const float* w[14]; };

__global__ void convert_weights(W14 p, bf16* __restrict__ wsb)
{
    const int z = blockIdx.z;
    const int tid = threadIdx.x;
    int wi, n0, N_;
    if (z < 13) { wi = z; n0 = blockIdx.y * 32; N_ = 512; }
    else        { wi = 13; n0 = (z - 13) * 512 + blockIdx.y * 32; N_ = 4096; }
    const int k0 = blockIdx.x * 32;
    const float* W = p.w[wi];
    const long base = (wi < 13) ? (long)wi * 524288 : 6815744L;
    const long hsz  = (wi < 13) ? 262144L : 2097152L;
    bf16* hi = wsb + base;
    bf16* lo = wsb + base + hsz;

    __shared__ float tile[32][33];
    #pragma unroll
    for (int i = 0; i < 4; i++) {
        const int idx = i * 256 + tid;
        const int r = idx >> 5, c = idx & 31;
        tile[r][c] = W[(long)(k0 + r) * N_ + n0 + c];
    }
    __syncthreads();
    #pragma unroll
    for (int i = 0; i < 4; i++) {
        const int idx = i * 256 + tid;
        const int r = idx >> 5, c = idx & 31;
        const float v = tile[c][r];
        const bf16 h = (bf16)v;
        const long o = (long)(n0 + r) * 512 + k0 + c;
        hi[o] = h;
        lo[o] = (bf16)(v - (float)h);
    }
}

// ---------------------------------------------------------------- f32 activation -> hilo split (elementwise)
__global__ void convert_x(const float* __restrict__ x,
                          bf16* __restrict__ hi, bf16* __restrict__ lo)
{
    const long i = ((long)blockIdx.x * 256 + threadIdx.x) * 8;
    float4 f0 = ((const float4*)(x + i))[0], f1 = ((const float4*)(x + i))[1];
    float v[8] = {f0.x, f0.y, f0.z, f0.w, f1.x, f1.y, f1.z, f1.w};
    bf16x8 hh, ll; cvt8(v, hh, ll);
    *(bf16x8*)&hi[i] = hh;
    *(bf16x8*)&lo[i] = ll;
}

// ---------------------------------------------------------------- fused flash attention v9 (best verified: 4-way KV split)
__global__ __launch_bounds__(128, 2)
void flash_attn(const float* __restrict__ Q,
                const bf16* __restrict__ Khi, const bf16* __restrict__ Klo,
                const bf16* __restrict__ Vthi, const bf16* __restrict__ Vtlo,
                float* __restrict__ Op, float* __restrict__ ml)
{
    constexpr int N = 4096, D = 512, SPAN = 1024, TKV = 32, NT = SPAN / TKV;
    constexpr float TS = 0.12751791f;   // (1/sqrt(128)) * log2(e)

    __shared__ __align__(16) bf16 smem[16384];   // 32 KB
    bf16* Kh = smem;
    bf16* Kl = smem + 4096;
    bf16* Vh = smem + 8192;
    bf16* Vl = smem + 12288;

    const int tid = threadIdx.x;
    const int wave = tid >> 6, lane = tid & 63;
    const int fr = lane & 15, fq = lane >> 4;
    const int qt = blockIdx.x, h = blockIdx.y, s = blockIdx.z;
    const long q0 = (long)qt * 64;

    const int kn = tid >> 4, kk8 = tid & 15;
    const int vd = tid >> 2, vk8 = tid & 3;

    bf16x8 qh[2][4], ql[2][4];
    #pragma unroll
    for (int rg = 0; rg < 2; rg++)
        #pragma unroll
        for (int kt = 0; kt < 4; kt++) {
            const float* src = Q + (q0 + wave * 32 + rg * 16 + fr) * D + h * 128 + kt * 32 + fq * 8;
            float4 f0 = ((const float4*)src)[0], f1 = ((const float4*)src)[1];
            float v[8] = {f0.x, f0.y, f0.z, f0.w, f1.x, f1.y, f1.z, f1.w};
            cvt8(v, qh[rg][kt], ql[rg][kt]);
        }

    f32x4v o[2][8] = {};
    float m_run[2] = {-1e30f, -1e30f}, l_run[2] = {0.f, 0.f};

    const int j0base = s * SPAN;

    #pragma unroll 1
    for (int jt = 0; jt < NT; jt++) {
        const int j0 = j0base + jt * TKV;

        #pragma unroll
        for (int i = 0; i < 4; i++) {
            const int n = kn + 8 * i;
            const long kg = (long)(j0 + n) * D + h * 128 + kk8 * 8;
            const int ko = n * 128 + ((kk8 ^ (n & 15)) << 3);
            *(uint4*)&Kh[ko] = *(const uint4*)&Khi[kg];
            *(uint4*)&Kl[ko] = *(const uint4*)&Klo[kg];
            const int d = vd + 32 * i;
            const long vg = (long)(h * 128 + d) * N + j0 + vk8 * 8;
            const int vo = d * 32 + ((vk8 ^ ((d >> 2) & 3)) << 3);
            *(uint4*)&Vh[vo] = *(const uint4*)&Vthi[vg];
            *(uint4*)&Vl[vo] = *(const uint4*)&Vtlo[vg];
        }
        __syncthreads();

        f32x4v sacc[2][2] = {};
        #pragma unroll
        for (int jb = 0; jb < 2; jb++) {
            bf16x8 kh[4], km[4];
            #pragma unroll
            for (int kt = 0; kt < 4; kt++) {
                const int off = (jb * 16 + fr) * 128 + (((kt * 4 + fq) ^ fr) << 3);
                kh[kt] = *(const bf16x8*)&Kh[off];
                km[kt] = *(const bf16x8*)&Kl[off];
            }
            __builtin_amdgcn_s_setprio(1);
            #pragma unroll
            for (int kt = 0; kt < 4; kt++)
                #pragma unroll
                for (int rg = 0; rg < 2; rg++) {
                    sacc[rg][jb] = __builtin_amdgcn_mfma_f32_16x16x32_bf16(km[kt], qh[rg][kt], sacc[rg][jb], 0, 0, 0);
                    sacc[rg][jb] = __builtin_amdgcn_mfma_f32_16x16x32_bf16(kh[kt], ql[rg][kt], sacc[rg][jb], 0, 0, 0);
                    sacc[rg][jb] = __builtin_amdgcn_mfma_f32_16x16x32_bf16(kh[kt], qh[rg][kt], sacc[rg][jb], 0, 0, 0);
                }
            __builtin_amdgcn_s_setprio(0);
        }

        bf16x8 ph[2], pl[2];
        float alpha[2];
        #pragma unroll
        for (int rg = 0; rg < 2; rg++) {
            float t[2][4];
            float mloc = -1e30f;
            #pragma unroll
            for (int jb = 0; jb < 2; jb++)
                #pragma unroll
                for (int r = 0; r < 4; r++) {
                    t[jb][r] = sacc[rg][jb][r] * TS;
                    mloc = fmaxf(mloc, t[jb][r]);
                }
            mloc = fmaxf(mloc, __shfl_xor(mloc, 16));
            mloc = fmaxf(mloc, __shfl_xor(mloc, 32));
            const float mn = fmaxf(m_run[rg], mloc);
            alpha[rg] = exp2f(m_run[rg] - mn);
            m_run[rg] = mn;

            float p[2][4];
            float rs = 0.f;
            #pragma unroll
            for (int jb = 0; jb < 2; jb++)
                #pragma unroll
                for (int r = 0; r < 4; r++) {
                    p[jb][r] = exp2f(t[jb][r] - mn);
                    rs += p[jb][r];
                }
            rs += __shfl_xor(rs, 16);
            rs += __shfl_xor(rs, 32);
            l_run[rg] = l_run[rg] * alpha[rg] + rs;

            unsigned int hp[2][2], lp[2][2];
            #pragma unroll
            for (int jb = 0; jb < 2; jb++)
                #pragma unroll
                for (int t2 = 0; t2 < 2; t2++) {
                    const float p0 = p[jb][2 * t2], p1 = p[jb][2 * t2 + 1];
                    const bf16 h0 = (bf16)p0, h1 = (bf16)p1;
                    const unsigned short u0 = __builtin_bit_cast(unsigned short, h0);
                    const unsigned short u1 = __builtin_bit_cast(unsigned short, h1);
                    hp[jb][t2] = (unsigned int)u0 | ((unsigned int)u1 << 16);
                    const bf16 g0 = (bf16)(p0 - (float)h0), g1 = (bf16)(p1 - (float)h1);
                    const unsigned short w0 = __builtin_bit_cast(unsigned short, g0);
                    const unsigned short w1 = __builtin_bit_cast(unsigned short, g1);
                    lp[jb][t2] = (unsigned int)w0 | ((unsigned int)w1 << 16);
                }

            uint4 PH, PL;
            {
                unsigned int phw[4], plw[4];
                #pragma unroll
                for (int w = 0; w < 4; w++) {
                    const int src = ((2 * (fq & 1) + (w >> 1)) << 4) + fr;
                    const unsigned int h0 = (unsigned int)__shfl((int)hp[0][w & 1], src);
                    const unsigned int h1 = (unsigned int)__shfl((int)hp[1][w & 1], src);
                    phw[w] = (fq >> 1) ? h1 : h0;
                    const unsigned int g0 = (unsigned int)__shfl((int)lp[0][w & 1], src);
                    const unsigned int g1 = (unsigned int)__shfl((int)lp[1][w & 1], src);
                    plw[w] = (fq >> 1) ? g1 : g0;
                }
                PH.x = phw[0]; PH.y = phw[1]; PH.z = phw[2]; PH.w = phw[3];
                PL.x = plw[0]; PL.y = plw[1]; PL.z = plw[2]; PL.w = plw[3];
            }
            ph[rg] = __builtin_bit_cast(bf16x8, PH);
            pl[rg] = __builtin_bit_cast(bf16x8, PL);
        }

        #pragma unroll
        for (int rg = 0; rg < 2; rg++) {
            float alr[4];
            #pragma unroll
            for (int r = 0; r < 4; r++) alr[r] = __shfl(alpha[rg], fq * 4 + r);
            #pragma unroll
            for (int jbo = 0; jbo < 8; jbo++)
                #pragma unroll
                for (int r = 0; r < 4; r++)
                    o[rg][jbo][r] *= alr[r];
        }

        #pragma unroll
        for (int jbo = 0; jbo < 8; jbo++) {
            const int off = (jbo * 16 + fr) * 32 + ((fq ^ ((fr >> 2) & 3)) << 3);
            const bf16x8 vh_ = *(const bf16x8*)&Vh[off];
            const bf16x8 vl_ = *(const bf16x8*)&Vl[off];
            __builtin_amdgcn_s_setprio(1);
            #pragma unroll
            for (int rg = 0; rg < 2; rg++) {
                o[rg][jbo] = __builtin_amdgcn_mfma_f32_16x16x32_bf16(pl[rg], vh_, o[rg][jbo], 0, 0, 0);
                o[rg][jbo] = __builtin_amdgcn_mfma_f32_16x16x32_bf16(ph[rg], vl_, o[rg][jbo], 0, 0, 0);
                o[rg][jbo] = __builtin_amdgcn_mfma_f32_16x16x32_bf16(ph[rg], vh_, o[rg][jbo], 0, 0, 0);
            }
            __builtin_amdgcn_s_setprio(0);
        }
        __syncthreads();
    }

    const long sidx = (long)((h * 64 + qt) * 4 + s);
    float* ob = Op + sidx * 8192;
    #pragma unroll
    for (int rg = 0; rg < 2; rg++)
        #pragma unroll
        for (int jbo = 0; jbo < 8; jbo++)
            #pragma unroll
            for (int r = 0; r < 4; r++) {
                const int lrow = wave * 32 + rg * 16 + fq * 4 + r;
                ob[lrow * 128 + jbo * 16 + fr] = o[rg][jbo][r];
            }
    if (fq == 0) {
        #pragma unroll
        for (int rg = 0; rg < 2; rg++) {
            const int lrow = wave * 32 + rg * 16 + fr;
            ml[sidx * 128 + lrow]      = m_run[rg];
            ml[sidx * 128 + 64 + lrow] = l_run[rg];
        }
    }
}

// ---------------------------------------------------------------- merge 4 KV-splits (exact); optional hilo ctx out
template<bool OUTH>
__global__ void flash_merge_t(const float* __restrict__ Op, const float* __restrict__ ml,
                              float* __restrict__ ctx, bf16* __restrict__ ch, bf16* __restrict__ cl)
{
    const int idx = blockIdx.x;            // h*64 + qt, 256 blocks
    const int h = idx >> 6, qt = idx & 63;
    const int tid = threadIdx.x;
    __shared__ float es[4][64], il[64];
    if (tid < 64) {
        float m[4], l[4];
        #pragma unroll
        for (int s = 0; s < 4; s++) {
            m[s] = ml[(long)(idx * 4 + s) * 128 + tid];
            l[s] = ml[(long)(idx * 4 + s) * 128 + 64 + tid];
        }
        float mx = fmaxf(fmaxf(m[0], m[1]), fmaxf(m[2], m[3]));
        float denom = 0.f;
        #pragma unroll
        for (int s = 0; s < 4; s++) {
            const float e = exp2f(m[s] - mx);
            es[s][tid] = e;
            denom += e * l[s];
        }
        il[tid] = 1.f / denom;
    }
    __syncthreads();
    const long b = (long)idx * 4 * 8192;
    #pragma unroll
    for (int i = 0; i < 32; i++) {
        const int e = tid + i * 256;
        const int row = e >> 7, col = e & 127;
        float v = es[0][row] * Op[b + e] + es[1][row] * Op[b + 8192 + e]
                + es[2][row] * Op[b + 16384 + e] + es[3][row] * Op[b + 24576 + e];
        const float vv = v * il[row];
        const long cidx = (long)(qt * 64 + row) * 512 + h * 128 + col;
        ctx[cidx] = vv;
        if (OUTH) {
            const bf16 hh = (bf16)vv;
            ch[cidx] = hh;
            cl[cidx] = (bf16)(vv - (float)hh);
        }
    }
}

// ---------------------------------------------------------------- residual + layernorm; optional hilo out
template<bool OUTH>
__global__ void add_ln_t(const float* __restrict__ a, const float* __restrict__ b,
                         const float* __restrict__ g, const float* __restrict__ be,
                         float* __restrict__ out, bf16* __restrict__ oh, bf16* __restrict__ ol)
{
    const long row = blockIdx.x;
    const int tid = threadIdx.x;
    const long base = row * 512L;
    float x0 = a[base + tid]       + b[base + tid];
    float x1 = a[base + tid + 256] + b[base + tid + 256];
    float s = block_reduce_sum256(x0 + x1);
    float mu = s * (1.f / 512.f);
    float d0 = x0 - mu, d1 = x1 - mu;
    float var = block_reduce_sum256(d0 * d0 + d1 * d1) * (1.f / 512.f);
    float invs = rsqrtf(var + 1e-6f);
    const float y0 = d0 * invs * g[tid]       + be[tid];
    const float y1 = d1 * invs * g[tid + 256] + be[tid + 256];
    out[base + tid]       = y0;
    out[base + tid + 256] = y1;
    if (OUTH) {
        const bf16 h0 = (bf16)y0, h1 = (bf16)y1;
        oh[base + tid]       = h0;
        ol[base + tid]       = (bf16)(y0 - (float)h0);
        oh[base + tid + 256] = h1;
        ol[base + tid + 256] = (bf16)(y1 - (float)h1);
    }
}

// ---------------------------------------------------------------- normalize emb rows (legacy f32 out)
__global__ void normalize_emb(const float* __restrict__ emb, float* __restrict__ embn)
{
    const long row = blockIdx.x;
    const int tid = threadIdx.x;
    const long base = row * 512L;
    float a0 = emb[base + tid];
    float a1 = emb[base + tid + 256];
    float ss = block_reduce_sum256(a0 * a0 + a1 * a1);
    float sc = rsqrtf(fmaxf(ss, 1e-12f));
    embn[base + tid]       = a0 * sc;
    embn[base + tid + 256] = a1 * sc;
}

// ---------------------------------------------------------------- normalize emb rows -> bf16 hi/lo
__global__ void normalize_emb_p(const float* __restrict__ emb,
                                bf16* __restrict__ hi, bf16* __restrict__ lo)
{
    const long row = blockIdx.x;
    const int tid = threadIdx.x;
    const long base = row * 512L;
    float a0 = emb[base + tid];
    float a1 = emb[base + tid + 256];
    float ss = block_reduce_sum256(a0 * a0 + a1 * a1);
    float sc = rsqrtf(fmaxf(ss, 1e-12f));
    const float e0 = a0 * sc, e1 = a1 * sc;
    const bf16 h0 = (bf16)e0, h1 = (bf16)e1;
    hi[base + tid]       = h0;
    lo[base + tid]       = (bf16)(e0 - (float)h0);
    hi[base + tid + 256] = h1;
    lo[base + tid + 256] = (bf16)(e1 - (float)h1);
}

// ---------------------------------------------------------------- VQ select; optional hilo vq_feat out
template<bool OUTH>
__global__ void vq_select_t(float* __restrict__ sims, const float* __restrict__ emb,
                            float* __restrict__ vq_out, bf16* __restrict__ vh, bf16* __restrict__ vl)
{
    __shared__ float sv[256];
    __shared__ int   si[256];
    const long row = blockIdx.x;
    const int tid = threadIdx.x;
    float* s = sims + row * 1024L;
    float v0 = s[tid], v1 = s[tid + 256], v2 = s[tid + 512], v3 = s[tid + 768];
    float best = v0; int bi = tid;
    if (v1 > best) { best = v1; bi = tid + 256; }
    if (v2 > best) { best = v2; bi = tid + 512; }
    if (v3 > best) { best = v3; bi = tid + 768; }
    sv[tid] = best; si[tid] = bi; __syncthreads();
    #pragma unroll
    for (int st = 128; st > 0; st >>= 1) {
        if (tid < st) {
            if (sv[tid + st] > sv[tid] ||
                (sv[tid + st] == sv[tid] && si[tid + st] < si[tid])) {
                sv[tid] = sv[tid + st]; si[tid] = si[tid + st];
            }
        }
        __syncthreads();
    }
    const int idx = si[0];
    s[tid]       = (tid       == idx) ? 1.f : 0.f;
    s[tid + 256] = (tid + 256 == idx) ? 1.f : 0.f;
    s[tid + 512] = (tid + 512 == idx) ? 1.f : 0.f;
    s[tid + 768] = (tid + 768 == idx) ? 1.f : 0.f;
    const float* er = emb + (long)idx * 512;
    float* vr = vq_out + row * 512L;
    const float e0 = er[tid], e1 = er[tid + 256];
    vr[tid]       = e0;
    vr[tid + 256] = e1;
    if (OUTH) {
        const bf16 h0 = (bf16)e0, h1 = (bf16)e1;
        vh[row * 512 + tid]       = h0;
        vl[row * 512 + tid]       = (bf16)(e0 - (float)h0);
        vh[row * 512 + tid + 256] = h1;
        vl[row * 512 + tid + 256] = (bf16)(e1 - (float)h1);
    }
}

// ---------------------------------------------------------------- host side
struct EncW {
    const float *wq, *wk, *wv, *wo, *w1, *w2;
    const float *bq, *bk, *bv, *bo, *b1, *b2;
    const float *g1, *be1, *g2, *be2;
};

static void run_encoder_g3(hipStream_t stream, const float* x, const EncW& w,
                           float* qb, bf16* khi, bf16* klo, bf16* vthi, bf16* vtlo,
                           float* ctx, float* Op, float* ml,
                           float* x1, float* hb, float* out)
{
    const int N = 4096, D = 512;
    qkv_gemm<<<dim3(12, 64), 256, 0, stream>>>(
        x, w.wq, w.wk, w.wv, w.bq, w.bk, w.bv, qb, khi, klo, vthi, vtlo);
    flash_attn<<<dim3(64, 4, 4), 128, 0, stream>>>(qb, khi, klo, vthi, vtlo, Op, ml);
    flash_merge_t<false><<<256, 256, 0, stream>>>(Op, ml, ctx, nullptr, nullptr);
    gemm3<64, false, false, true, false><<<dim3(4, 64), 256, 0, stream>>>(
        ctx, w.wo, w.bo, qb, nullptr, nullptr, D, D, D, D, 1.f);
    add_ln_t<false><<<N, 256, 0, stream>>>(x, qb, w.g1, w.be1, x1, nullptr, nullptr);
    gemm3<64, true, false, true, false><<<dim3(4, 64), 256, 0, stream>>>(
        x1, w.w1, w.b1, hb, nullptr, nullptr, D, D, D, D, 1.f);
    gemm3<64, false, false, true, false><<<dim3(4, 64), 256, 0, stream>>>(
        hb, w.w2, w.b2, qb, nullptr, nullptr, D, D, D, D, 1.f);
    add_ln_t<false><<<N, 256, 0, stream>>>(x1, qb, w.g2, w.be2, out, nullptr, nullptr);
}

static void run_encoder_g3p(hipStream_t stream, const float* x, const EncW& w,
                            bf16* wsb, int slot0,
                            float* qb, bf16* khi, bf16* klo, bf16* vthi, bf16* vtlo,
                            float* ctx, float* Op, float* ml,
                            float* x1, float* hb, float* out)
{
    const int N = 4096, D = 512;
    auto sh = [&](int i) { return wsb + (long)(slot0 + i) * 524288; };
    auto sl = [&](int i) { return wsb + (long)(slot0 + i) * 524288 + 262144; };
    qkv_gemmp<<<dim3(12, 64), 256, 0, stream>>>(
        x, sh(0), sl(0), sh(1), sl(1), sh(2), sl(2),
        w.bq, w.bk, w.bv, qb, khi, klo, vthi, vtlo);
    flash_attn<<<dim3(64, 4, 4), 128, 0, stream>>>(qb, khi, klo, vthi, vtlo, Op, ml);
    flash_merge_t<false><<<256, 256, 0, stream>>>(Op, ml, ctx, nullptr, nullptr);
    gemm3p<64, false><<<dim3(4, 64), 256, 0, stream>>>(
        ctx, sh(3), sl(3), w.bo, qb, D, D, D, D);
    add_ln_t<false><<<N, 256, 0, stream>>>(x, qb, w.g1, w.be1, x1, nullptr, nullptr);
    gemm3p<64, true><<<dim3(4, 64), 256, 0, stream>>>(
        x1, sh(4), sl(4), w.b1, hb, D, D, D, D);
    gemm3p<64, false><<<dim3(4, 64), 256, 0, stream>>>(
        hb, sh(5), sl(5), w.b2, qb, D, D, D, D);
    add_ln_t<false><<<N, 256, 0, stream>>>(x1, qb, w.g2, w.be2, out, nullptr, nullptr);
}

// v11 tier: all GEMM A-operands pre-split hi/lo
static void run_encoder_g3q(hipStream_t stream,
                            const float* xres,
                            const bf16* xah, const bf16* xal,
                            const EncW& w, bf16* wsb, int slot0,
                            bf16* ctxh, bf16* ctxl, bf16* x1h, bf16* x1l,
                            bf16* hbh, bf16* hbl, bf16* o2h, bf16* o2l,
                            float* qb, bf16* khi, bf16* klo, bf16* vthi, bf16* vtlo,
                            float* ctx, float* Op, float* ml,
                            float* x1, float* hb, float* out)
{
    const int N = 4096, D = 512;
    auto sh = [&](int i) { return wsb + (long)(slot0 + i) * 524288; };
    auto sl = [&](int i) { return wsb + (long)(slot0 + i) * 524288 + 262144; };
    qkv_gemmq<<<dim3(12, 64), 256, 0, stream>>>(
        xah, xal, sh(0), sl(0), sh(1), sl(1), sh(2), sl(2),
        w.bq, w.bk, w.bv, qb, khi, klo, vthi, vtlo);
    flash_attn<<<dim3(64, 4, 4), 128, 0, stream>>>(qb, khi, klo, vthi, vtlo, Op, ml);
    flash_merge_t<true><<<256, 256, 0, stream>>>(Op, ml, ctx, ctxh, ctxl);
    gemm3q<64, false, false><<<dim3(4, 64), 256, 0, stream>>>(
        ctxh, ctxl, sh(3), sl(3), w.bo, qb, nullptr, nullptr, D, D, D, D);
    add_ln_t<true><<<N, 256, 0, stream>>>(xres, qb, w.g1, w.be1, x1, x1h, x1l);
    gemm3q<64, true, true><<<dim3(4, 64), 256, 0, stream>>>(
        x1h, x1l, sh(4), sl(4), w.b1, hb, hbh, hbl, D, D, D, D);
    gemm3q<64, false, false><<<dim3(4, 64), 256, 0, stream>>>(
        hbh, hbl, sh(5), sl(5), w.b2, qb, nullptr, nullptr, D, D, D, D);
    add_ln_t<true><<<N, 256, 0, stream>>>(x1, qb, w.g2, w.be2, out, o2h, o2l);
}

extern "C" void kernel_launch(void* const* d_in, const int* in_sizes, int n_in,
                              void* d_out, int out_size, void* d_ws, size_t ws_size,
                              hipStream_t stream)
{
    const int N = 4096, D = 512, E = 512, F = 4096, KCB = 1024;
    (void)in_sizes; (void)n_in; (void)out_size;

    const float* x_in  = (const float*)d_in[0];
    const float* fc1_w = (const float*)d_in[33];
    const float* fc1_b = (const float*)d_in[34];
    const float* fc2_w = (const float*)d_in[35];
    const float* fc2_b = (const float*)d_in[36];
    const float* emb   = (const float*)d_in[37];

    float* out0 = (float*)d_out;                  // encoded [N,E]
    float* out1 = out0 + (size_t)N * E;           // vq_feat [N,E]
    float* out2 = out1 + (size_t)N * E;           // one_hot [N,K]
    float* out3 = out2 + (size_t)N * KCB;         // decoded [N,F]
    float* out4 = out3 + (size_t)N * F;           // emb copy

    char* arena = (char*)out3;
    const size_t MB = 1024 * 1024;
    float* qb     = (float*)(arena + 0 * MB);
    bf16*  khi    = (bf16*) (arena + 8 * MB);
    bf16*  klo    = (bf16*) (arena + 12 * MB);
    bf16*  vthi   = (bf16*) (arena + 16 * MB);
    bf16*  vtlo   = (bf16*) (arena + 20 * MB);
    float* ctx    = (float*)(arena + 24 * MB);
    float* Op     = (float*)(arena + 32 * MB);
    float* decout = (float*)(arena + 56 * MB);
    float* x1     = (float*)(arena + 16 * MB);
    float* hb     = (float*)(arena + 8 * MB);
    float* ml     = (float*)out4;
    float* embn   = out1;
    float* stage  = (float*)out4;

    EncW ew = { (const float*)d_in[1],  (const float*)d_in[2],  (const float*)d_in[3],
                (const float*)d_in[4],  (const float*)d_in[5],  (const float*)d_in[6],
                (const float*)d_in[7],  (const float*)d_in[8],  (const float*)d_in[9],
                (const float*)d_in[10], (const float*)d_in[11], (const float*)d_in[12],
                (const float*)d_in[13], (const float*)d_in[14], (const float*)d_in[15],
                (const float*)d_in[16] };
    EncW dw = { (const float*)d_in[17], (const float*)d_in[18], (const float*)d_in[19],
                (const float*)d_in[20], (const float*)d_in[21], (const float*)d_in[22],
                (const float*)d_in[23], (const float*)d_in[24], (const float*)d_in[25],
                (const float*)d_in[26], (const float*)d_in[27], (const float*)d_in[28],
                (const float*)d_in[29], (const float*)d_in[30], (const float*)d_in[31],
                (const float*)d_in[32] };

    const size_t WS_NEED1 = 24117248;    // v10 tier: weights + emb hilo
    const size_t WS_NEED2 = 74448896;    // v11 tier: + 6 activation hilo slots
    const bool pre2 = (d_ws != nullptr) && (ws_size >= WS_NEED2);
    const bool pre1 = !pre2 && (d_ws != nullptr) && (ws_size >= WS_NEED1);

    if (pre2 || pre1) {
        bf16* wsb = (bf16*)d_ws;
        bf16* f2h = wsb + 6815744;  bf16* f2l = f2h + 2097152;
        bf16* enh = wsb + 11010048; bf16* enl = enh + 524288;

        W14 ptrs;
        ptrs.w[0]  = ew.wq; ptrs.w[1]  = ew.wk; ptrs.w[2]  = ew.wv;
        ptrs.w[3]  = ew.wo; ptrs.w[4]  = ew.w1; ptrs.w[5]  = ew.w2;
        ptrs.w[6]  = dw.wq; ptrs.w[7]  = dw.wk; ptrs.w[8]  = dw.wv;
        ptrs.w[9]  = dw.wo; ptrs.w[10] = dw.w1; ptrs.w[11] = dw.w2;
        ptrs.w[12] = fc1_w; ptrs.w[13] = fc2_w;
        convert_weights<<<dim3(16, 16, 21), 256, 0, stream>>>(ptrs, wsb);
        normalize_emb_p<<<KCB, 256, 0, stream>>>(emb, enh, enl);

        if (pre2) {
            auto AH = [&](int s_) { return wsb + 12058624L + (long)s_ * 4194304; };
            auto AL = [&](int s_) { return wsb + 12058624L + (long)s_ * 4194304 + 2097152; };
            bf16 *xah = AH(0), *xal = AL(0);
            bf16 *cth = AH(1), *ctl = AL(1);
            bf16 *x1h = AH(2), *x1l = AL(2);
            bf16 *hbh = AH(3), *hbl = AL(3);
            bf16 *o2h = AH(4), *o2l = AL(4);
            bf16 *f1h = AH(5), *f1l = AL(5);

            convert_x<<<1024, 256, 0, stream>>>(x_in, xah, xal);

            // ---- phase E
            run_encoder_g3q(stream, x_in, xah, xal, ew, wsb, 0,
                            cth, ctl, x1h, x1l, hbh, hbl, o2h, o2l,
                            qb, khi, klo, vthi, vtlo, ctx, Op, ml, x1, hb, ctx);
            // ---- phase F: fc1 (A = o2h/o2l)
            gemm3q<64, false, true><<<dim3(4, 64), 256, 0, stream>>>(
                o2h, o2l, wsb + 12L * 524288, wsb + 12L * 524288 + 262144,
                fc1_b, out0, f1h, f1l, D, D, D, E);
            // ---- phase V: sims (A = f1h/f1l, B = emb hilo)
            gemm3q<128, false, false><<<dim3(8, 32), 256, 0, stream>>>(
                f1h, f1l, enh, enl, nullptr, out2, nullptr, nullptr, E, E, E, KCB);
            vq_select_t<true><<<N, 256, 0, stream>>>(out2, emb, out1, xah, xal);
            // ---- phase D
            run_encoder_g3q(stream, out1, xah, xal, dw, wsb, 6,
                            cth, ctl, x1h, x1l, hbh, hbl, o2h, o2l,
                            qb, khi, klo, vthi, vtlo, ctx, Op, ml, x1, hb, decout);
            // ---- phase G: fc2 single dispatch (A = o2h/o2l in ws -> no out3 aliasing)
            gemm3q<128, true, false><<<dim3(F / 128, N / 128), 256, 0, stream>>>(
                o2h, o2l, f2h, f2l, fc2_b, out3, nullptr, nullptr, D, D, D, F);

            (void)hipMemcpyAsync(out4, emb, (size_t)KCB * E * sizeof(float), hipMemcpyDeviceToDevice, stream);
        } else {
            // ---- v10 tier
            run_encoder_g3p(stream, x_in, ew, wsb, 0, qb, khi, klo, vthi, vtlo, ctx, Op, ml, x1, hb, ctx);
            gemm3p<64, false><<<dim3(4, 64), 256, 0, stream>>>(
                ctx, wsb + 12L * 524288, wsb + 12L * 524288 + 262144, fc1_b, out0, D, D, D, E);
            gemm3p<128, false><<<dim3(8, 32), 256, 0, stream>>>(
                out0, enh, enl, nullptr, out2, E, E, E, KCB);
            vq_select_t<false><<<N, 256, 0, stream>>>(out2, emb, out1, nullptr, nullptr);
            run_encoder_g3p(stream, out1, dw, wsb, 6, qb, khi, klo, vthi, vtlo, ctx, Op, ml, x1, hb, decout);
            (void)hipMemcpyAsync(stage, decout + (size_t)3584 * D, (size_t)512 * D * sizeof(float),
                                 hipMemcpyDeviceToDevice, stream);
            gemm3p<128, true><<<dim3(F / 128, 3584 / 128), 256, 0, stream>>>(
                decout, f2h, f2l, fc2_b, out3, D, D, D, F);
            gemm3p<128, true><<<dim3(F / 128, 512 / 128), 256, 0, stream>>>(
                stage, f2h, f2l, fc2_b, out3 + (size_t)3584 * F, D, D, D, F);
            (void)hipMemcpyAsync(out4, emb, (size_t)KCB * E * sizeof(float), hipMemcpyDeviceToDevice, stream);
        }
    } else {
        // ---- legacy fallback
        normalize_emb<<<KCB, 256, 0, stream>>>(emb, embn);
        run_encoder_g3(stream, x_in, ew, qb, khi, klo, vthi, vtlo, ctx, Op, ml, x1, hb, ctx);
        gemm3<64, false, false, true, false><<<dim3(4, 64), 256, 0, stream>>>(
            ctx, fc1_w, fc1_b, out0, nullptr, nullptr, D, D, E, E, 1.f);
        gemm3<128, false, false, false, false><<<dim3(8, 32), 256, 0, stream>>>(
            out0, embn, nullptr, out2, nullptr, nullptr, E, E, E, KCB, 1.f);
        vq_select_t<false><<<N, 256, 0, stream>>>(out2, emb, out1, nullptr, nullptr);
        run_encoder_g3(stream, out1, dw, qb, khi, klo, vthi, vtlo, ctx, Op, ml, x1, hb, decout);
        (void)hipMemcpyAsync(stage, decout + (size_t)3584 * D, (size_t)512 * D * sizeof(float),
                             hipMemcpyDeviceToDevice, stream);
        gemm3<128, true, false, true, false><<<dim3(F / 128, 3584 / 128), 256, 0, stream>>>(
            decout, fc2_w, fc2_b, out3, nullptr, nullptr, D, D, F, F, 1.f);
        gemm3<128, true, false, true, false><<<dim3(F / 128, 512 / 128), 256, 0, stream>>>(
            stage, fc2_w, fc2_b, out3 + (size_t)3584 * F, nullptr, nullptr, D, D, F, F, 1.f);
        (void)hipMemcpyAsync(out4, emb, (size_t)KCB * E * sizeof(float), hipMemcpyDeviceToDevice, stream);
    }
}